// Round 12
// baseline (909.099 us; speedup 1.0000x reference)
//
#include <hip/hip_runtime.h>
#include <hip/hip_bf16.h>
#include <math.h>

#define N_NODES 10000
#define DIM 512
#define TOPK 6
#define NHC 20         // half-chunks (512 cols) for the coarse logits pass
#define HCHUNK 512
#define NL 4           // per-lane top list depth
#define NCK 8          // per-half-chunk top list depth
#define NC2 16         // merged candidate count fed to f64 re-rank
#define SLOPE 0.01
#define LN_EPS 1e-5f
#define NB_COL 320     // colsum partial blocks

typedef short bf16x8 __attribute__((ext_vector_type(8)));   // 8 bf16 (4 VGPRs)
typedef float f32x4 __attribute__((ext_vector_type(4)));
typedef double f64x4 __attribute__((ext_vector_type(4)));

// ---- packed sort key: high 18 bits = monotone fp32, low 14 = 16383-idx ----
__device__ __forceinline__ unsigned pack_key(float v, int idx)
{
    unsigned b = __float_as_uint(v);
    unsigned m = b ^ ((unsigned)((int)b >> 31) | 0x80000000u);  // order-preserving
    return (m & 0xFFFFC000u) | (16383u - (unsigned)idx);
}

// sorted-descending insert on packed keys (v_min/v_max bubble)
template <int D>
__device__ __forceinline__ void insert_u(unsigned (&k)[D], unsigned nk)
{
    if (nk > k[D - 1]) {
        k[D - 1] = nk;
#pragma unroll
        for (int s = D - 1; s > 0; s--) {
            unsigned hi = max(k[s], k[s - 1]);
            unsigned lo = min(k[s], k[s - 1]);
            k[s - 1] = hi; k[s] = lo;
        }
    }
}

__device__ __forceinline__ void gload16(const void* g, void* l)
{
    __builtin_amdgcn_global_load_lds(
        (const __attribute__((address_space(1))) void*)g,
        (__attribute__((address_space(3))) void*)l, 16, 0, 0);
}

// --------------------------- column mean of h (f64) ------------------------
__global__ __launch_bounds__(256) void colsum_part64(
    const double* __restrict__ h, double* __restrict__ part, int n, int nb)
{
    int b = blockIdx.x;
    int rows_per = (n + nb - 1) / nb;
    int r0 = b * rows_per, r1 = min(n, r0 + rows_per);
    int t = threadIdx.x;
    double s0 = 0.0, s1 = 0.0;
    for (int i = r0; i < r1; i++) {
        s0 += h[(size_t)i * DIM + t];
        s1 += h[(size_t)i * DIM + t + 256];
    }
    part[b * DIM + t] = s0;
    part[b * DIM + t + 256] = s1;
}

__global__ void colmean64(const double* __restrict__ part, double* __restrict__ mean,
                          int nb, int n)
{
    int j = blockIdx.x * blockDim.x + threadIdx.x;
    if (j < DIM) {
        double s = 0.0;
        for (int b = 0; b < nb; b++) s += part[b * DIM + j];
        mean[j] = s / (double)n;
    }
}

// kv_w and lin_w f32 -> bf16, 4 elems/thread
__global__ void cast_wb(const float* __restrict__ in1, short* __restrict__ o1, int n1,
                        const float* __restrict__ in2, short* __restrict__ o2)
{
    int i = (blockIdx.x * blockDim.x + threadIdx.x) * 4;
    const float* in = (i < n1) ? in1 + i : in2 + (i - n1);
    short* o = (i < n1) ? o1 + i : o2 + (i - n1);
    float4 f = *(const float4*)in;
    __hip_bfloat16 b0 = __float2bfloat16(f.x), b1 = __float2bfloat16(f.y);
    __hip_bfloat16 b2 = __float2bfloat16(f.z), b3 = __float2bfloat16(f.w);
    *(short4*)o = make_short4(*(short*)&b0, *(short*)&b1, *(short*)&b2, *(short*)&b3);
}

// -------------- f64 MFMA GEMM for fc1:  h = leaky(x @ fc1^T + b) ------------
// BM=64, BN=128, BK=32 (half the barriers of BK=16). XCD-grouped 1D grid.
// Row pad 33 doubles: stride 66 dwords == 2 mod 32 -> conflict-free (as 17).
__global__ __launch_bounds__(256, 3) void gemm_fc1(
    const float* __restrict__ X, const float* __restrict__ W,
    const float* __restrict__ bias, double* __restrict__ C, int n)
{
    const int K = DIM, M = DIM;
    const int id = blockIdx.x;
    const int c = id & 7, kk2 = id >> 3;
    const int y = kk2 & 3, mm = kk2 >> 2;
    const int bx = c + 8 * mm;
    if (bx >= (n + 63) / 64) return;

    __shared__ double As[64][33];
    __shared__ double Bs[128][33];
    const int t = threadIdx.x, lane = t & 63, wid = t >> 6;
    const int lx = lane & 15, q = lane >> 4;
    const int wr = (wid >> 1) * 32, wc = (wid & 1) * 64;
    const int i0 = bx * 64, j0 = y * 128;

    f64x4 acc[2][4];
#pragma unroll
    for (int a = 0; a < 2; a++)
#pragma unroll
        for (int b = 0; b < 4; b++) acc[a][b] = (f64x4)0.0;

    const int arow = t >> 2, askq = (t & 3) * 8;
    int gi = i0 + arow; if (gi >= n) gi = n - 1;
    const float* af32 = X + (size_t)gi * K + askq;
    const int brow = t >> 1, bskq = (t & 1) * 16;
    const float* wrow = W + (size_t)(j0 + brow) * K + bskq;

    float4 wv0 = *(const float4*)(wrow);
    float4 wv1 = *(const float4*)(wrow + 4);
    float4 wv2 = *(const float4*)(wrow + 8);
    float4 wv3 = *(const float4*)(wrow + 12);
    float4 av0 = *(const float4*)(af32);
    float4 av1 = *(const float4*)(af32 + 4);

    for (int k0 = 0; k0 < K; k0 += 32) {
        __syncthreads();
        As[arow][askq]     = (double)av0.x; As[arow][askq + 1] = (double)av0.y;
        As[arow][askq + 2] = (double)av0.z; As[arow][askq + 3] = (double)av0.w;
        As[arow][askq + 4] = (double)av1.x; As[arow][askq + 5] = (double)av1.y;
        As[arow][askq + 6] = (double)av1.z; As[arow][askq + 7] = (double)av1.w;
        Bs[brow][bskq]      = (double)wv0.x; Bs[brow][bskq + 1]  = (double)wv0.y;
        Bs[brow][bskq + 2]  = (double)wv0.z; Bs[brow][bskq + 3]  = (double)wv0.w;
        Bs[brow][bskq + 4]  = (double)wv1.x; Bs[brow][bskq + 5]  = (double)wv1.y;
        Bs[brow][bskq + 6]  = (double)wv1.z; Bs[brow][bskq + 7]  = (double)wv1.w;
        Bs[brow][bskq + 8]  = (double)wv2.x; Bs[brow][bskq + 9]  = (double)wv2.y;
        Bs[brow][bskq + 10] = (double)wv2.z; Bs[brow][bskq + 11] = (double)wv2.w;
        Bs[brow][bskq + 12] = (double)wv3.x; Bs[brow][bskq + 13] = (double)wv3.y;
        Bs[brow][bskq + 14] = (double)wv3.z; Bs[brow][bskq + 15] = (double)wv3.w;
        if (k0 + 32 < K) {
            wv0 = *(const float4*)(wrow + k0 + 32);
            wv1 = *(const float4*)(wrow + k0 + 36);
            wv2 = *(const float4*)(wrow + k0 + 40);
            wv3 = *(const float4*)(wrow + k0 + 44);
            av0 = *(const float4*)(af32 + k0 + 32);
            av1 = *(const float4*)(af32 + k0 + 36);
        }
        __syncthreads();

#pragma unroll
        for (int ks = 0; ks < 8; ks++) {
            double a0 = As[wr + lx][ks * 4 + q];
            double a1 = As[wr + 16 + lx][ks * 4 + q];
#pragma unroll
            for (int cf = 0; cf < 4; cf++) {
                double b = Bs[wc + cf * 16 + lx][ks * 4 + q];
                acc[0][cf] = __builtin_amdgcn_mfma_f64_16x16x4f64(a0, b, acc[0][cf], 0, 0, 0);
                acc[1][cf] = __builtin_amdgcn_mfma_f64_16x16x4f64(a1, b, acc[1][cf], 0, 0, 0);
            }
        }
    }

#pragma unroll
    for (int rf = 0; rf < 2; rf++)
#pragma unroll
        for (int cf = 0; cf < 4; cf++)
#pragma unroll
            for (int reg = 0; reg < 4; reg++) {
                int gi2 = i0 + wr + rf * 16 + q * 4 + reg;
                int gj2 = j0 + wc + cf * 16 + lx;
                if (gi2 < n) {
                    double v = acc[rf][cf][reg] + (double)bias[gj2];
                    v = (v >= 0.0) ? v : v * SLOPE;
                    C[(size_t)gi2 * M + gj2] = v;
                }
            }
}

// ---- f64 MFMA dual GEMM: e_h AND e_t = ((h+mean)*0.5) @ w^T + b, fused -----
// BK=32; XCD-grouped 1D grid (1280): c=id&7, y=(id>>3)&7, bx=c+8*(id>>6).
__global__ __launch_bounds__(256, 3) void gemm_ehet(
    const double* __restrict__ H, const float* __restrict__ whw,
    const float* __restrict__ whb, const float* __restrict__ wtw,
    const float* __restrict__ wtb, const double* __restrict__ mn,
    double* __restrict__ ehd, float* __restrict__ ehf, short* __restrict__ ehb2,
    double* __restrict__ etd, short* __restrict__ etb2, int n)
{
    const int K = DIM, M = DIM;
    const int id = blockIdx.x;
    const int c = id & 7, kk2 = id >> 3;
    const int y = kk2 & 7, mm = kk2 >> 3;
    const int bx = c + 8 * mm;
    if (bx >= (n + 63) / 64) return;
    const bool isH = (y < 4);
    const float* W    = isH ? whw : wtw;
    const float* bias = isH ? whb : wtb;
    double* C  = isH ? ehd : etd;
    short*  ob = isH ? ehb2 : etb2;

    __shared__ double As[64][33];
    __shared__ double Bs[128][33];
    const int t = threadIdx.x, lane = t & 63, wid = t >> 6;
    const int lx = lane & 15, q = lane >> 4;
    const int wr = (wid >> 1) * 32, wc = (wid & 1) * 64;
    const int i0 = bx * 64, j0 = (y & 3) * 128;

    f64x4 acc[2][4];
#pragma unroll
    for (int a = 0; a < 2; a++)
#pragma unroll
        for (int b = 0; b < 4; b++) acc[a][b] = (f64x4)0.0;

    const int arow = t >> 2, askq = (t & 3) * 8;
    int gi = i0 + arow; if (gi >= n) gi = n - 1;
    const double* af64 = H + (size_t)gi * K + askq;
    const int brow = t >> 1, bskq = (t & 1) * 16;
    const float* wrow = W + (size_t)(j0 + brow) * K + bskq;

    float4 wv0 = *(const float4*)(wrow);
    float4 wv1 = *(const float4*)(wrow + 4);
    float4 wv2 = *(const float4*)(wrow + 8);
    float4 wv3 = *(const float4*)(wrow + 12);
    double2 a0v = *(const double2*)(af64);
    double2 a1v = *(const double2*)(af64 + 2);
    double2 a2v = *(const double2*)(af64 + 4);
    double2 a3v = *(const double2*)(af64 + 6);

    for (int k0 = 0; k0 < K; k0 += 32) {
        __syncthreads();
        double2 mv0 = *(const double2*)(mn + k0 + askq);
        double2 mv1 = *(const double2*)(mn + k0 + askq + 2);
        double2 mv2 = *(const double2*)(mn + k0 + askq + 4);
        double2 mv3 = *(const double2*)(mn + k0 + askq + 6);
        As[arow][askq]     = (a0v.x + mv0.x) * 0.5; As[arow][askq + 1] = (a0v.y + mv0.y) * 0.5;
        As[arow][askq + 2] = (a1v.x + mv1.x) * 0.5; As[arow][askq + 3] = (a1v.y + mv1.y) * 0.5;
        As[arow][askq + 4] = (a2v.x + mv2.x) * 0.5; As[arow][askq + 5] = (a2v.y + mv2.y) * 0.5;
        As[arow][askq + 6] = (a3v.x + mv3.x) * 0.5; As[arow][askq + 7] = (a3v.y + mv3.y) * 0.5;
        Bs[brow][bskq]      = (double)wv0.x; Bs[brow][bskq + 1]  = (double)wv0.y;
        Bs[brow][bskq + 2]  = (double)wv0.z; Bs[brow][bskq + 3]  = (double)wv0.w;
        Bs[brow][bskq + 4]  = (double)wv1.x; Bs[brow][bskq + 5]  = (double)wv1.y;
        Bs[brow][bskq + 6]  = (double)wv1.z; Bs[brow][bskq + 7]  = (double)wv1.w;
        Bs[brow][bskq + 8]  = (double)wv2.x; Bs[brow][bskq + 9]  = (double)wv2.y;
        Bs[brow][bskq + 10] = (double)wv2.z; Bs[brow][bskq + 11] = (double)wv2.w;
        Bs[brow][bskq + 12] = (double)wv3.x; Bs[brow][bskq + 13] = (double)wv3.y;
        Bs[brow][bskq + 14] = (double)wv3.z; Bs[brow][bskq + 15] = (double)wv3.w;
        if (k0 + 32 < K) {
            wv0 = *(const float4*)(wrow + k0 + 32);
            wv1 = *(const float4*)(wrow + k0 + 36);
            wv2 = *(const float4*)(wrow + k0 + 40);
            wv3 = *(const float4*)(wrow + k0 + 44);
            a0v = *(const double2*)(af64 + k0 + 32);
            a1v = *(const double2*)(af64 + k0 + 34);
            a2v = *(const double2*)(af64 + k0 + 36);
            a3v = *(const double2*)(af64 + k0 + 38);
        }
        __syncthreads();

#pragma unroll
        for (int ks = 0; ks < 8; ks++) {
            double a0 = As[wr + lx][ks * 4 + q];
            double a1 = As[wr + 16 + lx][ks * 4 + q];
#pragma unroll
            for (int cf = 0; cf < 4; cf++) {
                double b = Bs[wc + cf * 16 + lx][ks * 4 + q];
                acc[0][cf] = __builtin_amdgcn_mfma_f64_16x16x4f64(a0, b, acc[0][cf], 0, 0, 0);
                acc[1][cf] = __builtin_amdgcn_mfma_f64_16x16x4f64(a1, b, acc[1][cf], 0, 0, 0);
            }
        }
    }

#pragma unroll
    for (int rf = 0; rf < 2; rf++)
#pragma unroll
        for (int cf = 0; cf < 4; cf++)
#pragma unroll
            for (int reg = 0; reg < 4; reg++) {
                int gi2 = i0 + wr + rf * 16 + q * 4 + reg;
                int gj2 = j0 + wc + cf * 16 + lx;
                if (gi2 < n) {
                    double v = acc[rf][cf][reg] + (double)bias[gj2];
                    size_t idx = (size_t)gi2 * M + gj2;
                    C[idx] = v;
                    float f = (float)v;
                    if (isH) ehf[idx] = f;
                    __hip_bfloat16 bb = __float2bfloat16(f);
                    ob[idx] = *reinterpret_cast<short*>(&bb);
                }
            }
}

// ---------------- bf16 MFMA logits + fused per-half-chunk top-8 ------------
// v2: 256-row tile (rf=4): 12 ds_read feed 32 MFMA/wave/phase (was 10:16).
// Grid 800 = 40 row-blocks x 20 half-chunks; XCD decode: hc%8 -> XCD, so
// 2 B-panels (1 MB) L2-resident per XCD. BK=32, 2 LDS buffers (48 KB),
// vmcnt(6) counted (6 loads/thread/phase). Packed-key top lists.
__global__ __launch_bounds__(256, 2) void logits_topk_mfma(
    const short* __restrict__ eh, const short* __restrict__ et,
    unsigned* __restrict__ pk, int n)
{
    __shared__ short As[2][8192];   // 256 rows x 32 shorts
    __shared__ short Bs[2][4096];   // 128 rows x 32 shorts
    const int t = threadIdx.x;
    const int lane = t & 63, wid = t >> 6;
    const int lx = lane & 15, q = lane >> 4;

    int id = blockIdx.x, bx, hc;
    if (id < 640) { hc = id & 15; bx = id >> 4; }
    else { int r = id - 640; hc = 16 + (r & 3); bx = r >> 2; }
    const int i0 = bx * 256;
    const int wbase = wid * 64;

    const int jlo = hc * HCHUNK;
    const int jhi = min(n, jlo + HCHUNK);
    const int nj = (jhi - jlo + 127) >> 7;
    const int np = nj * 16;

    // staging: issue is covers LDS row = is*64 + (t>>2), slot = t&3;
    // source slot pre-swizzled: (t&3) ^ ((row>>1)&3) = (t&3) ^ ((t>>3)&3)
    const int sslot = (t & 3) ^ ((t >> 3) & 3);
    const short* aP[4];
    const short* bP[2];
#pragma unroll
    for (int is = 0; is < 4; is++) {
        int row = is * 64 + (t >> 2);
        int ra = i0 + row; if (ra >= n) ra = n - 1;
        aP[is] = eh + (size_t)ra * DIM + sslot * 8;
    }
    const int slotq = (q ^ ((lx >> 1) & 3)) * 8;
    const int aOff = (wbase + lx) * 32 + slotq;
    const int bOff = lx * 32 + slotq;

    unsigned keys[16][NL];
#pragma unroll
    for (int r = 0; r < 16; r++)
#pragma unroll
        for (int s = 0; s < NL; s++) keys[r][s] = 0u;

    f32x4 acc[4][8];
#pragma unroll
    for (int rf = 0; rf < 4; rf++)
#pragma unroll
        for (int cf = 0; cf < 8; cf++) acc[rf][cf] = (f32x4)0.f;

    auto STAGE = [&](int buf, int ph) {
        int kk = ph & 15;
        if (kk == 0) {  // new j-tile: refresh B row pointers (1/16 stages)
            int j0 = jlo + (ph >> 4) * 128;
#pragma unroll
            for (int is = 0; is < 2; is++) {
                int row = is * 64 + (t >> 2);
                int rb = j0 + row; if (rb >= n) rb = n - 1;
                bP[is] = et + (size_t)rb * DIM + sslot * 8;
            }
        }
        int ko = kk * 32;
#pragma unroll
        for (int is = 0; is < 4; is++)
            gload16(aP[is] + ko, &As[buf][is * 2048 + wid * 512]);
#pragma unroll
        for (int is = 0; is < 2; is++)
            gload16(bP[is] + ko, &Bs[buf][is * 2048 + wid * 512]);
    };

    STAGE(0, 0);
    for (int p = 0; p < np; ++p) {
        // barrier A: all waves done READING buf[(p+1)&1]
        __builtin_amdgcn_sched_barrier(0);
        __builtin_amdgcn_s_barrier();
        __builtin_amdgcn_sched_barrier(0);
        if (p + 1 < np) {
            STAGE((p + 1) & 1, p + 1);
            asm volatile("s_waitcnt vmcnt(6)" ::: "memory");  // phase p's 6 loads
        } else {
            asm volatile("s_waitcnt vmcnt(0)" ::: "memory");
        }
        __builtin_amdgcn_sched_barrier(0);
        __builtin_amdgcn_s_barrier();   // barrier B: buf[p&1] visible
        __builtin_amdgcn_sched_barrier(0);

        const short* Ab = As[p & 1];
        const short* Bb = Bs[p & 1];
        bf16x8 a0 = *(const bf16x8*)(Ab + aOff);
        bf16x8 a1 = *(const bf16x8*)(Ab + aOff + 512);
        bf16x8 a2 = *(const bf16x8*)(Ab + aOff + 1024);
        bf16x8 a3 = *(const bf16x8*)(Ab + aOff + 1536);
#pragma unroll
        for (int cf = 0; cf < 8; cf++) {
            bf16x8 bw = *(const bf16x8*)(Bb + bOff + cf * 512);
            acc[0][cf] = __builtin_amdgcn_mfma_f32_16x16x32_bf16(a0, bw, acc[0][cf], 0, 0, 0);
            acc[1][cf] = __builtin_amdgcn_mfma_f32_16x16x32_bf16(a1, bw, acc[1][cf], 0, 0, 0);
            acc[2][cf] = __builtin_amdgcn_mfma_f32_16x16x32_bf16(a2, bw, acc[2][cf], 0, 0, 0);
            acc[3][cf] = __builtin_amdgcn_mfma_f32_16x16x32_bf16(a3, bw, acc[3][cf], 0, 0, 0);
        }

        if ((p & 15) == 15) {   // end of a j-tile: pack+insert top-4, reset acc
            int j0 = jlo + (p >> 4) * 128;
#pragma unroll
            for (int rf = 0; rf < 4; rf++)
#pragma unroll
                for (int cf = 0; cf < 8; cf++) {
                    int gj = j0 + cf * 16 + lx;
                    if (gj < n) {
#pragma unroll
                        for (int reg = 0; reg < 4; reg++)
                            insert_u<NL>(keys[rf * 4 + reg],
                                         pack_key(acc[rf][cf][reg], gj));
                    }
                    acc[rf][cf] = (f32x4)0.f;
                }
        }
    }

    // butterfly merge across the 16-lane group -> per-(hc,row) top-8
#pragma unroll
    for (int rr = 0; rr < 16; rr++) {
        unsigned mk[NCK];
#pragma unroll
        for (int s = 0; s < NL; s++) mk[s] = keys[rr][s];
#pragma unroll
        for (int s = NL; s < NCK; s++) mk[s] = 0u;
        for (int m = 1; m < 16; m <<= 1) {
            unsigned sv[NCK];
#pragma unroll
            for (int s = 0; s < NCK; s++) sv[s] = mk[s];
#pragma unroll
            for (int s = 0; s < NCK; s++) {
                unsigned ov = (unsigned)__shfl_xor((int)sv[s], m);
                insert_u<NCK>(mk, ov);
            }
        }
        if (lx == 0) {
            int rf = rr >> 2, reg = rr & 3;
            int grow = i0 + wbase + rf * 16 + q * 4 + reg;
            if (grow < n) {
#pragma unroll
                for (int s = 0; s < NCK; s++)
                    pk[((size_t)hc * N_NODES + grow) * NCK + s] = mk[s];
            }
        }
    }
}

// ------------- bf16 MFMA GEMM:  C = post(A @ W^T + bias)  (K=512) ----------
// XCD-grouped 1D grid: c=id&7, y=(id>>3)&(NY-1), bx=c+8*(id>>(3+LY)).
template <int POST, int NY, int LY>
__global__ __launch_bounds__(256, 3) void mfma_gemm_bf16(
    const short* __restrict__ A, const short* __restrict__ W,
    const float* __restrict__ bias, const float* __restrict__ res,
    float* __restrict__ C, int n, int M)
{
    const int id = blockIdx.x;
    const int c = id & 7, kk2 = id >> 3;
    const int y = kk2 & (NY - 1), mm = kk2 >> LY;
    const int bxx = c + 8 * mm;
    if (bxx >= (n + 127) / 128) return;

    __shared__ short As[2][8192];
    __shared__ short Bs[2][8192];
    const int t = threadIdx.x;
    const int lane = t & 63, wid = t >> 6;
    const int lx = lane & 15, q = lane >> 4;
    const int lx7 = lane & 7;
    const int i0 = bxx * 128;
    const int j0 = y * 128;
    const int wbase = wid * 32;
    const int srl = lane >> 3;
    const int swz = (lane & 7) ^ srl;

    const short* aP[4];
    const short* bP[4];
#pragma unroll
    for (int is = 0; is < 4; is++) {
        int ra = i0 + is * 32 + wid * 8 + srl; if (ra >= n) ra = n - 1;
        aP[is] = A + (size_t)ra * DIM + swz * 8;
        int rb = j0 + is * 32 + wid * 8 + srl;   // M multiple of 128
        bP[is] = W + (size_t)rb * DIM + swz * 8;
    }
    int aIdx[2], bIdx[2];
#pragma unroll
    for (int ks = 0; ks < 2; ks++) {
        int kap = (ks * 4 + q) ^ lx7;
        aIdx[ks] = (wbase + lx) * 64 + kap * 8;
        bIdx[ks] = lx * 64 + kap * 8;
    }

    f32x4 acc[2][8];
#pragma unroll
    for (int rf = 0; rf < 2; rf++)
#pragma unroll
        for (int cf = 0; cf < 8; cf++) acc[rf][cf] = (f32x4)0.f;

    auto STAGE = [&](int buf, int kk) {
        int ko = kk * 64;
        short* ab = &As[buf][wid * 512];
        short* bb = &Bs[buf][wid * 512];
#pragma unroll
        for (int is = 0; is < 4; is++) {
            gload16(aP[is] + ko, ab + is * 2048);
            gload16(bP[is] + ko, bb + is * 2048);
        }
    };

    STAGE(0, 0);
    for (int p = 0; p < 8; ++p) {
        __builtin_amdgcn_sched_barrier(0);
        __builtin_amdgcn_s_barrier();
        __builtin_amdgcn_sched_barrier(0);
        if (p + 1 < 8) {
            STAGE((p + 1) & 1, p + 1);
            asm volatile("s_waitcnt vmcnt(8)" ::: "memory");
        } else {
            asm volatile("s_waitcnt vmcnt(0)" ::: "memory");
        }
        __builtin_amdgcn_sched_barrier(0);
        __builtin_amdgcn_s_barrier();
        __builtin_amdgcn_sched_barrier(0);

        const short* Ab = As[p & 1];
        const short* Bb = Bs[p & 1];
#pragma unroll
        for (int ks = 0; ks < 2; ks++) {
            bf16x8 a0 = *(const bf16x8*)(Ab + aIdx[ks]);
            bf16x8 a1 = *(const bf16x8*)(Ab + aIdx[ks] + 1024);
#pragma unroll
            for (int cf = 0; cf < 8; cf++) {
                bf16x8 bw = *(const bf16x8*)(Bb + bIdx[ks] + cf * 1024);
                acc[0][cf] = __builtin_amdgcn_mfma_f32_16x16x32_bf16(
                    a0, bw, acc[0][cf], 0, 0, 0);
                acc[1][cf] = __builtin_amdgcn_mfma_f32_16x16x32_bf16(
                    a1, bw, acc[1][cf], 0, 0, 0);
            }
        }
    }

#pragma unroll
    for (int rf = 0; rf < 2; rf++)
#pragma unroll
        for (int cf = 0; cf < 8; cf++)
#pragma unroll
            for (int reg = 0; reg < 4; reg++) {
                int gi = i0 + wbase + rf * 16 + q * 4 + reg;
                int gj = j0 + cf * 16 + lx;
                if (gi < n) {
                    float v = acc[rf][cf][reg] + bias[gj];
                    if (POST >= 1) v = (v >= 0.f) ? v : v * SLOPE;
                    if (POST == 2) v += res[(size_t)gi * M + gj];
                    C[(size_t)gi * M + gj] = v;
                }
            }
}

// merge 20 half-chunk lists of 8 packed keys -> top-16 indices per row
__global__ void merge_chunks16(const unsigned* __restrict__ pk,
                               int* __restrict__ cand, int n)
{
    int row = blockIdx.x * blockDim.x + threadIdx.x;
    if (row >= n) return;
    unsigned bk[NC2];
#pragma unroll
    for (int s = 0; s < NC2; s++) bk[s] = 0u;
    for (int c = 0; c < NHC; c++) {
#pragma unroll
        for (int s = 0; s < NCK; s++)
            insert_u<NC2>(bk, pk[((size_t)c * n + row) * NCK + s]);
    }
#pragma unroll
    for (int s = 0; s < NC2; s++)
        cand[row * NC2 + s] = 16383 - (int)(bk[s] & 16383u);
}

// ------- f64 re-rank of the 16 candidates + fused neighbor counting --------
__global__ __launch_bounds__(256) void refine16(
    const double* __restrict__ ehd, const double* __restrict__ etd,
    const int* __restrict__ cand, int* __restrict__ tki,
    int* __restrict__ counts, int n)
{
    int row = blockIdx.x * 4 + (threadIdx.x >> 6);
    if (row >= n) return;
    int lane = threadIdx.x & 63;
    int c = lane >> 2, sub = lane & 3;
    int j = cand[row * NC2 + c];
    const double* er = ehd + (size_t)row * DIM;
    const double* tr = etd + (size_t)j * DIM;
    double s = 0.0;
#pragma unroll 8
    for (int k = sub; k < DIM; k += 4) s += er[k] * tr[k];
    s += __shfl_down(s, 2);
    s += __shfl_down(s, 1);
    double mine = __shfl(s, lane & ~3);
    int rank = 0;
#pragma unroll
    for (int m = 0; m < NC2; m++) {
        double vm = __shfl(s, m * 4);
        int jm = __shfl(j, m * 4);
        bool better = (vm > mine) || (vm == mine && jm < j);
        rank += better ? 1 : 0;
    }
    if (sub == 0 && rank < TOPK) {
        tki[row * TOPK + rank] = j;
        atomicAdd(&counts[j], 1);
    }
}

// ----------------------------- argmax / ins_top ----------------------------
__global__ __launch_bounds__(1024) void argmax_kernel(
    const int* __restrict__ counts, int n, const float* __restrict__ x,
    int* __restrict__ topn, float* __restrict__ out_ins)
{
    __shared__ unsigned long long red[1024];
    int t = threadIdx.x;
    unsigned long long best = 0;
    for (int j = t; j < n; j += 1024) {
        unsigned long long key =
            ((unsigned long long)(unsigned)counts[j] << 32) | (unsigned)(n - 1 - j);
        if (key > best) best = key;
    }
    red[t] = best;
    __syncthreads();
    for (int s = 512; s > 0; s >>= 1) {
        if (t < s && red[t + s] > red[t]) red[t] = red[t + s];
        __syncthreads();
    }
    int tn = n - 1 - (int)(red[0] & 0xffffffffu);
    if (t == 0) *topn = tn;
    if (t < DIM) out_ins[t] = x[(size_t)tn * DIM + t];
}

// ------------------------------- q heads -----------------------------------
__global__ __launch_bounds__(512) void qheads_kernel(
    const double* __restrict__ h2d, const double* __restrict__ mn,
    const int* __restrict__ topn, const float* __restrict__ qw,
    const float* __restrict__ qb, float* __restrict__ qh)
{
    __shared__ float qf[DIM];
    int t = threadIdx.x;
    int tn = *topn;
    qf[t] = (float)((h2d[(size_t)tn * DIM + t] + mn[t]) * 0.5);
    __syncthreads();
    int w = t >> 6, lane = t & 63;
    int jrow = blockIdx.x * 8 + w;
    float s = 0.f;
    for (int k = lane; k < DIM; k += 64) s += qf[k] * qw[(size_t)jrow * DIM + k];
#pragma unroll
    for (int m = 32; m > 0; m >>= 1) s += __shfl_down(s, m);
    if (lane == 0) qh[jrow] = (s + qb[jrow]) * 0.125f;
}

__global__ __launch_bounds__(512) void scores_kernel(
    const float* __restrict__ E, const float* __restrict__ qh, float* __restrict__ sc)
{
    int i = blockIdx.x;
    int t = threadIdx.x, w = t >> 6, lane = t & 63;
    float v = qh[t] * E[(size_t)i * 1024 + t];
#pragma unroll
    for (int m = 32; m > 0; m >>= 1) v += __shfl_down(v, m);
    if (lane == 0) sc[i * 8 + w] = v;
}

// ---------------- attention + 2x layernorm (one block per node) ------------
__global__ __launch_bounds__(512) void attn_ln_kernel(
    const float* __restrict__ E, const float* __restrict__ sc,
    const int* __restrict__ tki, const float* __restrict__ eh,
    const float* __restrict__ nw, const float* __restrict__ nbias,
    short* __restrict__ sprb, int n)
{
    __shared__ int nb[TOPK];
    __shared__ float red[16];
    __shared__ float stats[2];
    const int i = blockIdx.x;
    const int t = threadIdx.x;
    const int h = t >> 6, lane = t & 63;
    if (t < TOPK) nb[t] = tki[i * TOPK + t];
    __syncthreads();

    float myse = 0.f;
    if (lane < TOPK) myse = sc[(size_t)nb[lane] * 8 + h];
    float se[TOPK];
#pragma unroll
    for (int e = 0; e < TOPK; e++) se[e] = __shfl(myse, e);
    float mx = se[0];
#pragma unroll
    for (int e = 1; e < TOPK; e++) mx = fmaxf(mx, se[e]);
    float wsum = 0.f, w[TOPK];
#pragma unroll
    for (int e = 0; e < TOPK; e++) { w[e] = expf(se[e] - mx); wsum += w[e]; }
    float inv = 1.f / wsum;

    float o = 0.f;
#pragma unroll
    for (int e = 0; e < TOPK; e++) o += w[e] * E[(size_t)nb[e] * 1024 + 512 + t];
    o *= inv;

    float s1 = o, s2 = o * o;
#pragma unroll
    for (int m = 32; m > 0; m >>= 1) { s1 += __shfl_down(s1, m); s2 += __shfl_down(s2, m); }
    if (lane == 0) { red[h] = s1; red[h + 8] = s2; }
    __syncthreads();
    if (t == 0) {
        float a = 0.f, b = 0.f;
#pragma unroll
        for (int k = 0; k < 8; k++) { a += red[k]; b += red[k + 8]; }
        float mu = a * (1.f / 512.f);
        float var = b * (1.f / 512.f) - mu * mu;
        stats[0] = mu; stats[1] = rsqrtf(var + LN_EPS);
    }
    __syncthreads();
    float enh = (o - stats[0]) * stats[1] * nw[t] + nbias[t];
    float t2 = eh[(size_t)i * DIM + t] + enh;
    __syncthreads();

    s1 = t2; s2 = t2 * t2;
#pragma unroll
    for (int m = 32; m > 0; m >>= 1) { s1 += __shfl_down(s1, m); s2 += __shfl_down(s2, m); }
    if (lane == 0) { red[h] = s1; red[h + 8] = s2; }
    __syncthreads();
    if (t == 0) {
        float a = 0.f, b = 0.f;
#pragma unroll
        for (int k = 0; k < 8; k++) { a += red[k]; b += red[k + 8]; }
        float mu = a * (1.f / 512.f);
        float var = b * (1.f / 512.f) - mu * mu;
        stats[0] = mu; stats[1] = rsqrtf(var + LN_EPS);
    }
    __syncthreads();
    float sv = (t2 - stats[0]) * stats[1] * nw[t] + nbias[t];
    __hip_bfloat16 bb = __float2bfloat16(sv);
    sprb[(size_t)i * DIM + t] = *reinterpret_cast<short*>(&bb);
}

// ===========================================================================
extern "C" void kernel_launch(void* const* d_in, const int* in_sizes, int n_in,
                              void* d_out, int out_size, void* d_ws, size_t ws_size,
                              hipStream_t stream)
{
    const float* x     = (const float*)d_in[0];
    const float* fc1_w = (const float*)d_in[1];
    const float* fc1_b = (const float*)d_in[2];
    const float* wh_w  = (const float*)d_in[3];
    const float* wh_b  = (const float*)d_in[4];
    const float* wt_w  = (const float*)d_in[5];
    const float* wt_b  = (const float*)d_in[6];
    const float* q_w   = (const float*)d_in[7];
    const float* q_b   = (const float*)d_in[8];
    const float* kv_w  = (const float*)d_in[9];
    const float* kv_b  = (const float*)d_in[10];
    const float* lin_w = (const float*)d_in[11];
    const float* lin_b = (const float*)d_in[12];
    const float* nw    = (const float*)d_in[13];
    const float* nbias = (const float*)d_in[14];
    float* out = (float*)d_out;

    const int n = N_NODES;
    size_t off = 0;
    auto take = [&](size_t bytes) -> void* {
        void* p = (void*)((char*)d_ws + off);
        off += (bytes + 255) & ~(size_t)255;
        return p;
    };
    double* h2d  = (double*)take((size_t)n * DIM * 8);  // RAW h (mix fused later)
    double* ehd  = (double*)take((size_t)n * DIM * 8);
    double* etd  = (double*)take((size_t)n * DIM * 8);
    float*  ehf  = (float*)take((size_t)n * DIM * 4);
    short*  ehb  = (short*)take((size_t)n * DIM * 2);
    short*  etb  = (short*)take((size_t)n * DIM * 2);
    short*  sprb = (short*)take((size_t)n * DIM * 2);
    unsigned* pk = (unsigned*)take((size_t)NHC * n * NCK * 4);
    int*    cand = (int*)take((size_t)n * NC2 * 4);
    int*    tki  = (int*)take((size_t)n * TOPK * 4);
    int*    counts = (int*)take((size_t)n * 4);
    int*    topn = (int*)take(256);
    float*  qh   = (float*)take(DIM * 4);
    float*  sc   = (float*)take((size_t)n * 8 * 4);
    double* part = (double*)take((size_t)NB_COL * DIM * 8);
    double* mean = (double*)take(DIM * 8);
    short*  kvwb = (short*)take((size_t)1024 * DIM * 2);
    short*  linwb = (short*)take((size_t)512 * DIM * 2);
    // alias (lifetimes disjoint, stream-ordered):
    float* E = (float*)h2d;   // n x 1024 f32: written after h2d's last read (qheads)

    hipMemsetAsync(counts, 0, n * sizeof(int), stream);

    dim3 b256(256);

    // h_raw = leaky(x @ fc1^T + b)   [f64 MFMA BK=32, XCD-grouped grid 640]
    gemm_fc1<<<dim3(640), b256, 0, stream>>>(x, fc1_w, fc1_b, h2d, n);
    colsum_part64<<<dim3(NB_COL), b256, 0, stream>>>(h2d, part, n, NB_COL);
    colmean64<<<dim3(2), b256, 0, stream>>>(part, mean, NB_COL, n);
    // e_h AND e_t = ((h_raw+mean)*0.5) @ w^T + b  [dual f64 MFMA BK=32]
    gemm_ehet<<<dim3(1280), b256, 0, stream>>>(
        h2d, wh_w, wh_b, wt_w, wt_b, mean, ehd, ehf, ehb, etd, etb, n);
    cast_wb<<<dim3((1536 * DIM) / 1024), b256, 0, stream>>>(
        kv_w, kvwb, 1024 * DIM, lin_w, linwb);

    // coarse bf16 MFMA logits (256-row tile) -> per-hc top-8 -> f64 re-rank
    logits_topk_mfma<<<dim3(800), b256, 0, stream>>>(ehb, etb, pk, n);
    merge_chunks16<<<dim3((n + 255) / 256), b256, 0, stream>>>(pk, cand, n);
    refine16<<<dim3((n + 3) / 4), b256, 0, stream>>>(ehd, etd, cand, tki, counts, n);

    argmax_kernel<<<dim3(1), dim3(1024), 0, stream>>>(counts, n, x, topn,
                                                      out + (size_t)n * DIM);
    qheads_kernel<<<dim3(64), dim3(512), 0, stream>>>(h2d, mean, topn, q_w, q_b, qh);
    // E = e_t @ kv_w^T + kv_b   [bf16 MFMA, XCD-grouped grid 640]
    mfma_gemm_bf16<0, 8, 3><<<dim3(640), b256, 0, stream>>>(
        etb, kvwb, kv_b, nullptr, E, n, 1024);
    scores_kernel<<<dim3(n), dim3(512), 0, stream>>>(E, qh, sc);
    attn_ln_kernel<<<dim3(n), dim3(512), 0, stream>>>(E, sc, tki, ehf, nw, nbias, sprb, n);
    // embedding = leaky(s @ lin^T + b) + x   [bf16 MFMA, XCD-grouped grid 320]
    mfma_gemm_bf16<2, 4, 2><<<dim3(320), b256, 0, stream>>>(
        sprb, linwb, lin_b, x, out, n, 512);
}

// Round 13
// 861.772 us; speedup vs baseline: 1.0549x; 1.0549x over previous
//
#include <hip/hip_runtime.h>
#include <hip/hip_bf16.h>
#include <math.h>

#define N_NODES 10000
#define DIM 512
#define TOPK 6
#define NCHUNK 10      // column chunks for the coarse logits pass
#define CHUNK 1024     // cols per chunk (last chunk: 784)
#define NL 4           // per-lane top list depth
#define NCK 8          // per-chunk top list depth
#define NC2 16         // merged candidate count fed to f64 re-rank
#define SLOPE 0.01
#define LN_EPS 1e-5f
#define NB_COL 320     // colsum partial blocks
#define FPAD 17        // f64 LDS row pad: bank=(34*lx+..)%32=2lx.. -> conflict-free

typedef short bf16x8 __attribute__((ext_vector_type(8)));   // 8 bf16 (4 VGPRs)
typedef float f32x4 __attribute__((ext_vector_type(4)));
typedef double f64x4 __attribute__((ext_vector_type(4)));

// ---- packed sort key: high 18 bits = monotone fp32, low 14 = 16383-idx ----
__device__ __forceinline__ unsigned pack_key(float v, int idx)
{
    unsigned b = __float_as_uint(v);
    unsigned m = b ^ ((unsigned)((int)b >> 31) | 0x80000000u);  // order-preserving
    return (m & 0xFFFFC000u) | (16383u - (unsigned)idx);
}

// sorted-descending insert on packed keys (v_min/v_max bubble)
template <int D>
__device__ __forceinline__ void insert_u(unsigned (&k)[D], unsigned nk)
{
    if (nk > k[D - 1]) {
        k[D - 1] = nk;
#pragma unroll
        for (int s = D - 1; s > 0; s--) {
            unsigned hi = max(k[s], k[s - 1]);
            unsigned lo = min(k[s], k[s - 1]);
            k[s - 1] = hi; k[s] = lo;
        }
    }
}

__device__ __forceinline__ void gload16(const void* g, void* l)
{
    __builtin_amdgcn_global_load_lds(
        (const __attribute__((address_space(1))) void*)g,
        (__attribute__((address_space(3))) void*)l, 16, 0, 0);
}

// --------------------------- column mean of h (f64) ------------------------
__global__ __launch_bounds__(256) void colsum_part64(
    const double* __restrict__ h, double* __restrict__ part, int n, int nb)
{
    int b = blockIdx.x;
    int rows_per = (n + nb - 1) / nb;
    int r0 = b * rows_per, r1 = min(n, r0 + rows_per);
    int t = threadIdx.x;
    double s0 = 0.0, s1 = 0.0;
    for (int i = r0; i < r1; i++) {
        s0 += h[(size_t)i * DIM + t];
        s1 += h[(size_t)i * DIM + t + 256];
    }
    part[b * DIM + t] = s0;
    part[b * DIM + t + 256] = s1;
}

__global__ void colmean64(const double* __restrict__ part, double* __restrict__ mean,
                          int nb, int n)
{
    int j = blockIdx.x * blockDim.x + threadIdx.x;
    if (j < DIM) {
        double s = 0.0;
        for (int b = 0; b < nb; b++) s += part[b * DIM + j];
        mean[j] = s / (double)n;
    }
}

// kv_w and lin_w f32 -> bf16, 4 elems/thread
__global__ void cast_wb(const float* __restrict__ in1, short* __restrict__ o1, int n1,
                        const float* __restrict__ in2, short* __restrict__ o2)
{
    int i = (blockIdx.x * blockDim.x + threadIdx.x) * 4;
    const float* in = (i < n1) ? in1 + i : in2 + (i - n1);
    short* o = (i < n1) ? o1 + i : o2 + (i - n1);
    float4 f = *(const float4*)in;
    __hip_bfloat16 b0 = __float2bfloat16(f.x), b1 = __float2bfloat16(f.y);
    __hip_bfloat16 b2 = __float2bfloat16(f.z), b3 = __float2bfloat16(f.w);
    *(short4*)o = make_short4(*(short*)&b0, *(short*)&b1, *(short*)&b2, *(short*)&b3);
}

// -------------- f64 MFMA GEMM for fc1:  h = leaky(x @ fc1^T + b) ------------
// BM=64, BN=128, BK=16; XCD-grouped 1D grid: c=id&7, y=(id>>3)&3,
// bx=c+8*(id>>5) -> all 4 j-panels of an A-panel on one XCD (L2 reuse).
__global__ __launch_bounds__(256, 4) void gemm_fc1(
    const float* __restrict__ X, const float* __restrict__ W,
    const float* __restrict__ bias, double* __restrict__ C, int n)
{
    const int K = DIM, M = DIM;
    const int id = blockIdx.x;
    const int c = id & 7, kk2 = id >> 3;
    const int y = kk2 & 3, mm = kk2 >> 2;
    const int bx = c + 8 * mm;
    if (bx >= (n + 63) / 64) return;

    __shared__ double As[64][FPAD];
    __shared__ double Bs[128][FPAD];
    const int t = threadIdx.x, lane = t & 63, wid = t >> 6;
    const int lx = lane & 15, q = lane >> 4;
    const int wr = (wid >> 1) * 32, wc = (wid & 1) * 64;
    const int i0 = bx * 64, j0 = y * 128;

    f64x4 acc[2][4];
#pragma unroll
    for (int a = 0; a < 2; a++)
#pragma unroll
        for (int b = 0; b < 4; b++) acc[a][b] = (f64x4)0.0;

    const int arow = t >> 2, askq = (t & 3) * 4;
    int gi = i0 + arow; if (gi >= n) gi = n - 1;
    const float* af32 = X + (size_t)gi * K + askq;
    const int brow = t >> 1, bskq = (t & 1) * 8;
    const float* wrow = W + (size_t)(j0 + brow) * K + bskq;

    float4 wv0 = *(const float4*)(wrow);
    float4 wv1 = *(const float4*)(wrow + 4);
    float4 av = *(const float4*)(af32);

    for (int k0 = 0; k0 < K; k0 += 16) {
        __syncthreads();
        As[arow][askq]     = (double)av.x; As[arow][askq + 1] = (double)av.y;
        As[arow][askq + 2] = (double)av.z; As[arow][askq + 3] = (double)av.w;
        Bs[brow][bskq]     = (double)wv0.x; Bs[brow][bskq + 1] = (double)wv0.y;
        Bs[brow][bskq + 2] = (double)wv0.z; Bs[brow][bskq + 3] = (double)wv0.w;
        Bs[brow][bskq + 4] = (double)wv1.x; Bs[brow][bskq + 5] = (double)wv1.y;
        Bs[brow][bskq + 6] = (double)wv1.z; Bs[brow][bskq + 7] = (double)wv1.w;
        if (k0 + 16 < K) {
            wv0 = *(const float4*)(wrow + k0 + 16);
            wv1 = *(const float4*)(wrow + k0 + 20);
            av  = *(const float4*)(af32 + k0 + 16);
        }
        __syncthreads();

#pragma unroll
        for (int ks = 0; ks < 4; ks++) {
            double a0 = As[wr + lx][ks * 4 + q];
            double a1 = As[wr + 16 + lx][ks * 4 + q];
#pragma unroll
            for (int cf = 0; cf < 4; cf++) {
                double b = Bs[wc + cf * 16 + lx][ks * 4 + q];
                acc[0][cf] = __builtin_amdgcn_mfma_f64_16x16x4f64(a0, b, acc[0][cf], 0, 0, 0);
                acc[1][cf] = __builtin_amdgcn_mfma_f64_16x16x4f64(a1, b, acc[1][cf], 0, 0, 0);
            }
        }
    }

#pragma unroll
    for (int rf = 0; rf < 2; rf++)
#pragma unroll
        for (int cf = 0; cf < 4; cf++)
#pragma unroll
            for (int reg = 0; reg < 4; reg++) {
                int gi2 = i0 + wr + rf * 16 + q * 4 + reg;
                int gj2 = j0 + wc + cf * 16 + lx;
                if (gi2 < n) {
                    double v = acc[rf][cf][reg] + (double)bias[gj2];
                    v = (v >= 0.0) ? v : v * SLOPE;
                    C[(size_t)gi2 * M + gj2] = v;
                }
            }
}

// ---- f64 MFMA dual GEMM: e_h AND e_t = ((h+mean)*0.5) @ w^T + b, fused -----
// XCD-grouped 1D grid (1280): c=id&7, y=(id>>3)&7, bx=c+8*(id>>6).
// launch_bounds (256,5): grid 1280 = exactly 5 blocks/CU, ALL co-resident
// (VGPR 64 <= 102 cap, LDS 26.1KB*5 = 130KB < 160KB) -> no generation tail.
__global__ __launch_bounds__(256, 5) void gemm_ehet(
    const double* __restrict__ H, const float* __restrict__ whw,
    const float* __restrict__ whb, const float* __restrict__ wtw,
    const float* __restrict__ wtb, const double* __restrict__ mn,
    double* __restrict__ ehd, float* __restrict__ ehf, short* __restrict__ ehb2,
    double* __restrict__ etd, short* __restrict__ etb2, int n)
{
    const int K = DIM, M = DIM;
    const int id = blockIdx.x;
    const int c = id & 7, kk2 = id >> 3;
    const int y = kk2 & 7, mm = kk2 >> 3;
    const int bx = c + 8 * mm;
    if (bx >= (n + 63) / 64) return;
    const bool isH = (y < 4);
    const float* W    = isH ? whw : wtw;
    const float* bias = isH ? whb : wtb;
    double* C  = isH ? ehd : etd;
    short*  ob = isH ? ehb2 : etb2;

    __shared__ double As[64][FPAD];
    __shared__ double Bs[128][FPAD];
    const int t = threadIdx.x, lane = t & 63, wid = t >> 6;
    const int lx = lane & 15, q = lane >> 4;
    const int wr = (wid >> 1) * 32, wc = (wid & 1) * 64;
    const int i0 = bx * 64, j0 = (y & 3) * 128;

    f64x4 acc[2][4];
#pragma unroll
    for (int a = 0; a < 2; a++)
#pragma unroll
        for (int b = 0; b < 4; b++) acc[a][b] = (f64x4)0.0;

    const int arow = t >> 2, askq = (t & 3) * 4;
    int gi = i0 + arow; if (gi >= n) gi = n - 1;
    const double* af64 = H + (size_t)gi * K + askq;
    const int brow = t >> 1, bskq = (t & 1) * 8;
    const float* wrow = W + (size_t)(j0 + brow) * K + bskq;

    float4 wv0 = *(const float4*)(wrow);
    float4 wv1 = *(const float4*)(wrow + 4);
    double2 a0v = *(const double2*)(af64);
    double2 a1v = *(const double2*)(af64 + 2);

    for (int k0 = 0; k0 < K; k0 += 16) {
        __syncthreads();
        double2 mv0 = *(const double2*)(mn + k0 + askq);
        double2 mv1 = *(const double2*)(mn + k0 + askq + 2);
        As[arow][askq]     = (a0v.x + mv0.x) * 0.5; As[arow][askq + 1] = (a0v.y + mv0.y) * 0.5;
        As[arow][askq + 2] = (a1v.x + mv1.x) * 0.5; As[arow][askq + 3] = (a1v.y + mv1.y) * 0.5;
        Bs[brow][bskq]     = (double)wv0.x; Bs[brow][bskq + 1] = (double)wv0.y;
        Bs[brow][bskq + 2] = (double)wv0.z; Bs[brow][bskq + 3] = (double)wv0.w;
        Bs[brow][bskq + 4] = (double)wv1.x; Bs[brow][bskq + 5] = (double)wv1.y;
        Bs[brow][bskq + 6] = (double)wv1.z; Bs[brow][bskq + 7] = (double)wv1.w;
        if (k0 + 16 < K) {
            wv0 = *(const float4*)(wrow + k0 + 16);
            wv1 = *(const float4*)(wrow + k0 + 20);
            a0v = *(const double2*)(af64 + k0 + 16);
            a1v = *(const double2*)(af64 + k0 + 18);
        }
        __syncthreads();

#pragma unroll
        for (int ks = 0; ks < 4; ks++) {
            double a0 = As[wr + lx][ks * 4 + q];
            double a1 = As[wr + 16 + lx][ks * 4 + q];
#pragma unroll
            for (int cf = 0; cf < 4; cf++) {
                double b = Bs[wc + cf * 16 + lx][ks * 4 + q];
                acc[0][cf] = __builtin_amdgcn_mfma_f64_16x16x4f64(a0, b, acc[0][cf], 0, 0, 0);
                acc[1][cf] = __builtin_amdgcn_mfma_f64_16x16x4f64(a1, b, acc[1][cf], 0, 0, 0);
            }
        }
    }

#pragma unroll
    for (int rf = 0; rf < 2; rf++)
#pragma unroll
        for (int cf = 0; cf < 4; cf++)
#pragma unroll
            for (int reg = 0; reg < 4; reg++) {
                int gi2 = i0 + wr + rf * 16 + q * 4 + reg;
                int gj2 = j0 + wc + cf * 16 + lx;
                if (gi2 < n) {
                    double v = acc[rf][cf][reg] + (double)bias[gj2];
                    size_t idx = (size_t)gi2 * M + gj2;
                    C[idx] = v;
                    float f = (float)v;
                    if (isH) ehf[idx] = f;
                    __hip_bfloat16 bb = __float2bfloat16(f);
                    ob[idx] = *reinterpret_cast<short*>(&bb);
                }
            }
}

// ---------------- bf16 MFMA logits + fused per-chunk top-8 -----------------
// EXACT R6 structure (203 us): grid 790, XCD-affinity decode, CHUNK=1024,
// BK=32, 2 LDS buffers (32 KB), m97 2-barrier skeleton, packed-key top lists.
__global__ __launch_bounds__(256, 3) void logits_topk_mfma(
    const short* __restrict__ eh, const short* __restrict__ et,
    unsigned* __restrict__ pk, int n)
{
    __shared__ short As[2][4096];   // 128 rows x 32 shorts
    __shared__ short Bs[2][4096];
    const int t = threadIdx.x;
    const int lane = t & 63, wid = t >> 6;
    const int lx = lane & 15, q = lane >> 4;

    int id = blockIdx.x, bx, chunk;
    if (id < 632) { chunk = id & 7; bx = id >> 3; }
    else { int r = id - 632; chunk = 8 + (r & 1); bx = r >> 1; }
    const int i0 = bx * 128;
    const int wbase = wid * 32;

    const int jlo = chunk * CHUNK;
    const int jhi = min(n, jlo + CHUNK);
    const int nj = (jhi - jlo + 127) >> 7;
    const int np = nj * 16;

    const int sslot = (t & 3) ^ ((t >> 3) & 3);
    const short* aP[2];
    const short* bP[2];
#pragma unroll
    for (int is = 0; is < 2; is++) {
        int row = is * 64 + (t >> 2);
        int ra = i0 + row; if (ra >= n) ra = n - 1;
        aP[is] = eh + (size_t)ra * DIM + sslot * 8;
    }
    const int slotq = (q ^ ((lx >> 1) & 3)) * 8;
    const int aOff = (wbase + lx) * 32 + slotq;
    const int bOff = lx * 32 + slotq;

    unsigned keys[8][NL];
#pragma unroll
    for (int r = 0; r < 8; r++)
#pragma unroll
        for (int s = 0; s < NL; s++) keys[r][s] = 0u;

    f32x4 acc[2][8];
#pragma unroll
    for (int rf = 0; rf < 2; rf++)
#pragma unroll
        for (int cf = 0; cf < 8; cf++) acc[rf][cf] = (f32x4)0.f;

    auto STAGE = [&](int buf, int ph) {
        int kk = ph & 15;
        if (kk == 0) {  // new j-tile: refresh B row pointers (1/16 stages)
            int j0 = jlo + (ph >> 4) * 128;
#pragma unroll
            for (int is = 0; is < 2; is++) {
                int row = is * 64 + (t >> 2);
                int rb = j0 + row; if (rb >= n) rb = n - 1;
                bP[is] = et + (size_t)rb * DIM + sslot * 8;
            }
        }
        int ko = kk * 32;
#pragma unroll
        for (int is = 0; is < 2; is++) {
            gload16(aP[is] + ko, &As[buf][is * 2048 + wid * 512]);
            gload16(bP[is] + ko, &Bs[buf][is * 2048 + wid * 512]);
        }
    };

    STAGE(0, 0);
    for (int p = 0; p < np; ++p) {
        __builtin_amdgcn_sched_barrier(0);
        __builtin_amdgcn_s_barrier();
        __builtin_amdgcn_sched_barrier(0);
        if (p + 1 < np) {
            STAGE((p + 1) & 1, p + 1);
            asm volatile("s_waitcnt vmcnt(4)" ::: "memory");
        } else {
            asm volatile("s_waitcnt vmcnt(0)" ::: "memory");
        }
        __builtin_amdgcn_sched_barrier(0);
        __builtin_amdgcn_s_barrier();
        __builtin_amdgcn_sched_barrier(0);

        const short* Ab = As[p & 1];
        const short* Bb = Bs[p & 1];
        bf16x8 a0 = *(const bf16x8*)(Ab + aOff);
        bf16x8 a1 = *(const bf16x8*)(Ab + aOff + 512);
#pragma unroll
        for (int cf = 0; cf < 8; cf++) {
            bf16x8 bw = *(const bf16x8*)(Bb + bOff + cf * 512);
            acc[0][cf] = __builtin_amdgcn_mfma_f32_16x16x32_bf16(
                a0, bw, acc[0][cf], 0, 0, 0);
            acc[1][cf] = __builtin_amdgcn_mfma_f32_16x16x32_bf16(
                a1, bw, acc[1][cf], 0, 0, 0);
        }

        if ((p & 15) == 15) {   // end of a j-tile: pack+insert top-4, reset acc
            int j0 = jlo + (p >> 4) * 128;
#pragma unroll
            for (int rf = 0; rf < 2; rf++)
#pragma unroll
                for (int cf = 0; cf < 8; cf++) {
                    int gj = j0 + cf * 16 + lx;
                    if (gj < n) {
#pragma unroll
                        for (int reg = 0; reg < 4; reg++)
                            insert_u<NL>(keys[rf * 4 + reg],
                                         pack_key(acc[rf][cf][reg], gj));
                    }
                    acc[rf][cf] = (f32x4)0.f;
                }
        }
    }

    // butterfly merge across the 16-lane group -> per-(chunk,row) top-8
#pragma unroll
    for (int rr = 0; rr < 8; rr++) {
        unsigned mk[NCK];
#pragma unroll
        for (int s = 0; s < NL; s++) mk[s] = keys[rr][s];
#pragma unroll
        for (int s = NL; s < NCK; s++) mk[s] = 0u;
        for (int m = 1; m < 16; m <<= 1) {
            unsigned sv[NCK];
#pragma unroll
            for (int s = 0; s < NCK; s++) sv[s] = mk[s];
#pragma unroll
            for (int s = 0; s < NCK; s++) {
                unsigned ov = (unsigned)__shfl_xor((int)sv[s], m);
                insert_u<NCK>(mk, ov);
            }
        }
        if (lx == 0) {
            int rf = rr >> 2, reg = rr & 3;
            int grow = i0 + wbase + rf * 16 + q * 4 + reg;
            if (grow < n) {
#pragma unroll
                for (int s = 0; s < NCK; s++)
                    pk[((size_t)chunk * N_NODES + grow) * NCK + s] = mk[s];
            }
        }
    }
}

// ------------- bf16 MFMA GEMM:  C = post(A @ W^T + bias)  (K=512) ----------
// XCD-grouped 1D grid: c=id&7, y=(id>>3)&(NY-1), bx=c+8*(id>>(3+LY)).
template <int POST, int NY, int LY>
__global__ __launch_bounds__(256, 3) void mfma_gemm_bf16(
    const short* __restrict__ A, const short* __restrict__ W,
    const float* __restrict__ bias, const float* __restrict__ res,
    float* __restrict__ C, int n, int M)
{
    const int id = blockIdx.x;
    const int c = id & 7, kk2 = id >> 3;
    const int y = kk2 & (NY - 1), mm = kk2 >> LY;
    const int bxx = c + 8 * mm;
    if (bxx >= (n + 127) / 128) return;

    __shared__ short As[2][8192];
    __shared__ short Bs[2][8192];
    const int t = threadIdx.x;
    const int lane = t & 63, wid = t >> 6;
    const int lx = lane & 15, q = lane >> 4;
    const int lx7 = lane & 7;
    const int i0 = bxx * 128;
    const int j0 = y * 128;
    const int wbase = wid * 32;
    const int srl = lane >> 3;
    const int swz = (lane & 7) ^ srl;

    const short* aP[4];
    const short* bP[4];
#pragma unroll
    for (int is = 0; is < 4; is++) {
        int ra = i0 + is * 32 + wid * 8 + srl; if (ra >= n) ra = n - 1;
        aP[is] = A + (size_t)ra * DIM + swz * 8;
        int rb = j0 + is * 32 + wid * 8 + srl;   // M multiple of 128
        bP[is] = W + (size_t)rb * DIM + swz * 8;
    }
    int aIdx[2], bIdx[2];
#pragma unroll
    for (int ks = 0; ks < 2; ks++) {
        int kap = (ks * 4 + q) ^ lx7;
        aIdx[ks] = (wbase + lx) * 64 + kap * 8;
        bIdx[ks] = lx * 64 + kap * 8;
    }

    f32x4 acc[2][8];
#pragma unroll
    for (int rf = 0; rf < 2; rf++)
#pragma unroll
        for (int cf = 0; cf < 8; cf++) acc[rf][cf] = (f32x4)0.f;

    auto STAGE = [&](int buf, int kk) {
        int ko = kk * 64;
        short* ab = &As[buf][wid * 512];
        short* bb = &Bs[buf][wid * 512];
#pragma unroll
        for (int is = 0; is < 4; is++) {
            gload16(aP[is] + ko, ab + is * 2048);
            gload16(bP[is] + ko, bb + is * 2048);
        }
    };

    STAGE(0, 0);
    for (int p = 0; p < 8; ++p) {
        __builtin_amdgcn_sched_barrier(0);
        __builtin_amdgcn_s_barrier();
        __builtin_amdgcn_sched_barrier(0);
        if (p + 1 < 8) {
            STAGE((p + 1) & 1, p + 1);
            asm volatile("s_waitcnt vmcnt(8)" ::: "memory");
        } else {
            asm volatile("s_waitcnt vmcnt(0)" ::: "memory");
        }
        __builtin_amdgcn_sched_barrier(0);
        __builtin_amdgcn_s_barrier();
        __builtin_amdgcn_sched_barrier(0);

        const short* Ab = As[p & 1];
        const short* Bb = Bs[p & 1];
#pragma unroll
        for (int ks = 0; ks < 2; ks++) {
            bf16x8 a0 = *(const bf16x8*)(Ab + aIdx[ks]);
            bf16x8 a1 = *(const bf16x8*)(Ab + aIdx[ks] + 1024);
#pragma unroll
            for (int cf = 0; cf < 8; cf++) {
                bf16x8 bw = *(const bf16x8*)(Bb + bIdx[ks] + cf * 1024);
                acc[0][cf] = __builtin_amdgcn_mfma_f32_16x16x32_bf16(
                    a0, bw, acc[0][cf], 0, 0, 0);
                acc[1][cf] = __builtin_amdgcn_mfma_f32_16x16x32_bf16(
                    a1, bw, acc[1][cf], 0, 0, 0);
            }
        }
    }

#pragma unroll
    for (int rf = 0; rf < 2; rf++)
#pragma unroll
        for (int cf = 0; cf < 8; cf++)
#pragma unroll
            for (int reg = 0; reg < 4; reg++) {
                int gi = i0 + wbase + rf * 16 + q * 4 + reg;
                int gj = j0 + cf * 16 + lx;
                if (gi < n) {
                    float v = acc[rf][cf][reg] + bias[gj];
                    if (POST >= 1) v = (v >= 0.f) ? v : v * SLOPE;
                    if (POST == 2) v += res[(size_t)gi * M + gj];
                    C[(size_t)gi * M + gj] = v;
                }
            }
}

// merge 10 chunk-lists of 8 packed keys -> top-16 indices per row
__global__ void merge_chunks16(const unsigned* __restrict__ pk,
                               int* __restrict__ cand, int n)
{
    int row = blockIdx.x * blockDim.x + threadIdx.x;
    if (row >= n) return;
    unsigned bk[NC2];
#pragma unroll
    for (int s = 0; s < NC2; s++) bk[s] = 0u;
    for (int c = 0; c < NCHUNK; c++) {
#pragma unroll
        for (int s = 0; s < NCK; s++)
            insert_u<NC2>(bk, pk[((size_t)c * n + row) * NCK + s]);
    }
#pragma unroll
    for (int s = 0; s < NC2; s++)
        cand[row * NC2 + s] = 16383 - (int)(bk[s] & 16383u);
}

// ------- f64 re-rank of the 16 candidates + fused neighbor counting --------
__global__ __launch_bounds__(256) void refine16(
    const double* __restrict__ ehd, const double* __restrict__ etd,
    const int* __restrict__ cand, int* __restrict__ tki,
    int* __restrict__ counts, int n)
{
    int row = blockIdx.x * 4 + (threadIdx.x >> 6);
    if (row >= n) return;
    int lane = threadIdx.x & 63;
    int c = lane >> 2, sub = lane & 3;
    int j = cand[row * NC2 + c];
    const double* er = ehd + (size_t)row * DIM;
    const double* tr = etd + (size_t)j * DIM;
    double s = 0.0;
#pragma unroll 8
    for (int k = sub; k < DIM; k += 4) s += er[k] * tr[k];
    s += __shfl_down(s, 2);
    s += __shfl_down(s, 1);
    double mine = __shfl(s, lane & ~3);
    int rank = 0;
#pragma unroll
    for (int m = 0; m < NC2; m++) {
        double vm = __shfl(s, m * 4);
        int jm = __shfl(j, m * 4);
        bool better = (vm > mine) || (vm == mine && jm < j);
        rank += better ? 1 : 0;
    }
    if (sub == 0 && rank < TOPK) {
        tki[row * TOPK + rank] = j;
        atomicAdd(&counts[j], 1);
    }
}

// ----------------------------- argmax / ins_top ----------------------------
__global__ __launch_bounds__(1024) void argmax_kernel(
    const int* __restrict__ counts, int n, const float* __restrict__ x,
    int* __restrict__ topn, float* __restrict__ out_ins)
{
    __shared__ unsigned long long red[1024];
    int t = threadIdx.x;
    unsigned long long best = 0;
    for (int j = t; j < n; j += 1024) {
        unsigned long long key =
            ((unsigned long long)(unsigned)counts[j] << 32) | (unsigned)(n - 1 - j);
        if (key > best) best = key;
    }
    red[t] = best;
    __syncthreads();
    for (int s = 512; s > 0; s >>= 1) {
        if (t < s && red[t + s] > red[t]) red[t] = red[t + s];
        __syncthreads();
    }
    int tn = n - 1 - (int)(red[0] & 0xffffffffu);
    if (t == 0) *topn = tn;
    if (t < DIM) out_ins[t] = x[(size_t)tn * DIM + t];
}

// ------------------------------- q heads -----------------------------------
__global__ __launch_bounds__(512) void qheads_kernel(
    const double* __restrict__ h2d, const double* __restrict__ mn,
    const int* __restrict__ topn, const float* __restrict__ qw,
    const float* __restrict__ qb, float* __restrict__ qh)
{
    __shared__ float qf[DIM];
    int t = threadIdx.x;
    int tn = *topn;
    qf[t] = (float)((h2d[(size_t)tn * DIM + t] + mn[t]) * 0.5);
    __syncthreads();
    int w = t >> 6, lane = t & 63;
    int jrow = blockIdx.x * 8 + w;
    float s = 0.f;
    for (int k = lane; k < DIM; k += 64) s += qf[k] * qw[(size_t)jrow * DIM + k];
#pragma unroll
    for (int m = 32; m > 0; m >>= 1) s += __shfl_down(s, m);
    if (lane == 0) qh[jrow] = (s + qb[jrow]) * 0.125f;
}

__global__ __launch_bounds__(512) void scores_kernel(
    const float* __restrict__ E, const float* __restrict__ qh, float* __restrict__ sc)
{
    int i = blockIdx.x;
    int t = threadIdx.x, w = t >> 6, lane = t & 63;
    float v = qh[t] * E[(size_t)i * 1024 + t];
#pragma unroll
    for (int m = 32; m > 0; m >>= 1) v += __shfl_down(v, m);
    if (lane == 0) sc[i * 8 + w] = v;
}

// ---------------- attention + 2x layernorm (one block per node) ------------
__global__ __launch_bounds__(512) void attn_ln_kernel(
    const float* __restrict__ E, const float* __restrict__ sc,
    const int* __restrict__ tki, const float* __restrict__ eh,
    const float* __restrict__ nw, const float* __restrict__ nbias,
    short* __restrict__ sprb, int n)
{
    __shared__ int nb[TOPK];
    __shared__ float red[16];
    __shared__ float stats[2];
    const int i = blockIdx.x;
    const int t = threadIdx.x;
    const int h = t >> 6, lane = t & 63;
    if (t < TOPK) nb[t] = tki[i * TOPK + t];
    __syncthreads();

    float myse = 0.f;
    if (lane < TOPK) myse = sc[(size_t)nb[lane] * 8 + h];
    float se[TOPK];
#pragma unroll
    for (int e = 0; e < TOPK; e++) se[e] = __shfl(myse, e);
    float mx = se[0];
#pragma unroll
    for (int e = 1; e < TOPK; e++) mx = fmaxf(mx, se[e]);
    float wsum = 0.f, w[TOPK];
#pragma unroll
    for (int e = 0; e < TOPK; e++) { w[e] = expf(se[e] - mx); wsum += w[e]; }
    float inv = 1.f / wsum;

    float o = 0.f;
#pragma unroll
    for (int e = 0; e < TOPK; e++) o += w[e] * E[(size_t)nb[e] * 1024 + 512 + t];
    o *= inv;

    float s1 = o, s2 = o * o;
#pragma unroll
    for (int m = 32; m > 0; m >>= 1) { s1 += __shfl_down(s1, m); s2 += __shfl_down(s2, m); }
    if (lane == 0) { red[h] = s1; red[h + 8] = s2; }
    __syncthreads();
    if (t == 0) {
        float a = 0.f, b = 0.f;
#pragma unroll
        for (int k = 0; k < 8; k++) { a += red[k]; b += red[k + 8]; }
        float mu = a * (1.f / 512.f);
        float var = b * (1.f / 512.f) - mu * mu;
        stats[0] = mu; stats[1] = rsqrtf(var + LN_EPS);
    }
    __syncthreads();
    float enh = (o - stats[0]) * stats[1] * nw[t] + nbias[t];
    float t2 = eh[(size_t)i * DIM + t] + enh;
    __syncthreads();

    s1 = t2; s2 = t2 * t2;
#pragma unroll
    for (int m = 32; m > 0; m >>= 1) { s1 += __shfl_down(s1, m); s2 += __shfl_down(s2, m); }
    if (lane == 0) { red[h] = s1; red[h + 8] = s2; }
    __syncthreads();
    if (t == 0) {
        float a = 0.f, b = 0.f;
#pragma unroll
        for (int k = 0; k < 8; k++) { a += red[k]; b += red[k + 8]; }
        float mu = a * (1.f / 512.f);
        float var = b * (1.f / 512.f) - mu * mu;
        stats[0] = mu; stats[1] = rsqrtf(var + LN_EPS);
    }
    __syncthreads();
    float sv = (t2 - stats[0]) * stats[1] * nw[t] + nbias[t];
    __hip_bfloat16 bb = __float2bfloat16(sv);
    sprb[(size_t)i * DIM + t] = *reinterpret_cast<short*>(&bb);
}

// ===========================================================================
extern "C" void kernel_launch(void* const* d_in, const int* in_sizes, int n_in,
                              void* d_out, int out_size, void* d_ws, size_t ws_size,
                              hipStream_t stream)
{
    const float* x     = (const float*)d_in[0];
    const float* fc1_w = (const float*)d_in[1];
    const float* fc1_b = (const float*)d_in[2];
    const float* wh_w  = (const float*)d_in[3];
    const float* wh_b  = (const float*)d_in[4];
    const float* wt_w  = (const float*)d_in[5];
    const float* wt_b  = (const float*)d_in[6];
    const float* q_w   = (const float*)d_in[7];
    const float* q_b   = (const float*)d_in[8];
    const float* kv_w  = (const float*)d_in[9];
    const float* kv_b  = (const float*)d_in[10];
    const float* lin_w = (const float*)d_in[11];
    const float* lin_b = (const float*)d_in[12];
    const float* nw    = (const float*)d_in[13];
    const float* nbias = (const float*)d_in[14];
    float* out = (float*)d_out;

    const int n = N_NODES;
    size_t off = 0;
    auto take = [&](size_t bytes) -> void* {
        void* p = (void*)((char*)d_ws + off);
        off += (bytes + 255) & ~(size_t)255;
        return p;
    };
    double* h2d  = (double*)take((size_t)n * DIM * 8);  // RAW h (mix fused later)
    double* ehd  = (double*)take((size_t)n * DIM * 8);
    double* etd  = (double*)take((size_t)n * DIM * 8);
    float*  ehf  = (float*)take((size_t)n * DIM * 4);
    short*  ehb  = (short*)take((size_t)n * DIM * 2);
    short*  etb  = (short*)take((size_t)n * DIM * 2);
    short*  sprb = (short*)take((size_t)n * DIM * 2);
    unsigned* pk = (unsigned*)take((size_t)NCHUNK * n * NCK * 4);
    int*    cand = (int*)take((size_t)n * NC2 * 4);
    int*    tki  = (int*)take((size_t)n * TOPK * 4);
    int*    counts = (int*)take((size_t)n * 4);
    int*    topn = (int*)take(256);
    float*  qh   = (float*)take(DIM * 4);
    float*  sc   = (float*)take((size_t)n * 8 * 4);
    double* part = (double*)take((size_t)NB_COL * DIM * 8);
    double* mean = (double*)take(DIM * 8);
    short*  kvwb = (short*)take((size_t)1024 * DIM * 2);
    short*  linwb = (short*)take((size_t)512 * DIM * 2);
    // alias (lifetimes disjoint, stream-ordered):
    float* E = (float*)h2d;   // n x 1024 f32: written after h2d's last read (qheads)

    hipMemsetAsync(counts, 0, n * sizeof(int), stream);

    dim3 b256(256);
    const int RB2 = (n + 127) / 128;  // 79

    // h_raw = leaky(x @ fc1^T + b)   [f64 MFMA, XCD-grouped grid 640]
    gemm_fc1<<<dim3(640), b256, 0, stream>>>(x, fc1_w, fc1_b, h2d, n);
    colsum_part64<<<dim3(NB_COL), b256, 0, stream>>>(h2d, part, n, NB_COL);
    colmean64<<<dim3(2), b256, 0, stream>>>(part, mean, NB_COL, n);
    // e_h AND e_t = ((h_raw+mean)*0.5) @ w^T + b  [dual f64 MFMA, 5 blocks/CU]
    gemm_ehet<<<dim3(1280), b256, 0, stream>>>(
        h2d, wh_w, wh_b, wt_w, wt_b, mean, ehd, ehf, ehb, etd, etb, n);
    cast_wb<<<dim3((1536 * DIM) / 1024), b256, 0, stream>>>(
        kv_w, kvwb, 1024 * DIM, lin_w, linwb);

    // coarse bf16 MFMA logits -> per-chunk top-8 keys -> top-16 -> f64 re-rank
    logits_topk_mfma<<<dim3(632 + 2 * RB2), b256, 0, stream>>>(ehb, etb, pk, n);
    merge_chunks16<<<dim3((n + 255) / 256), b256, 0, stream>>>(pk, cand, n);
    refine16<<<dim3((n + 3) / 4), b256, 0, stream>>>(ehd, etd, cand, tki, counts, n);

    argmax_kernel<<<dim3(1), dim3(1024), 0, stream>>>(counts, n, x, topn,
                                                      out + (size_t)n * DIM);
    qheads_kernel<<<dim3(64), dim3(512), 0, stream>>>(h2d, mean, topn, q_w, q_b, qh);
    // E = e_t @ kv_w^T + kv_b   [bf16 MFMA, XCD-grouped grid 640]
    mfma_gemm_bf16<0, 8, 3><<<dim3(640), b256, 0, stream>>>(
        etb, kvwb, kv_b, nullptr, E, n, 1024);
    scores_kernel<<<dim3(n), dim3(512), 0, stream>>>(E, qh, sc);
    attn_ln_kernel<<<dim3(n), dim3(512), 0, stream>>>(E, sc, tki, ehf, nw, nbias, sprb, n);
    // embedding = leaky(s @ lin^T + b) + x   [bf16 MFMA, XCD-grouped grid 320]
    mfma_gemm_bf16<2, 4, 2><<<dim3(320), b256, 0, stream>>>(
        sprb, linwb, lin_b, x, out, n, 512);
}

// Round 14
// 813.699 us; speedup vs baseline: 1.1172x; 1.0591x over previous
//
#include <hip/hip_runtime.h>
#include <hip/hip_bf16.h>
#include <math.h>

#define N_NODES 10000
#define DIM 512
#define TOPK 6
#define NCHUNK 10      // column chunks for the coarse logits pass
#define CHUNK 1024     // cols per chunk (last chunk: 784)
#define NL 4           // per-lane top list depth
#define NCK 8          // per-chunk top list depth
#define NC2 16         // merged candidate count fed to f64 re-rank
#define SLOPE 0.01
#define LN_EPS 1e-5f
#define NB_COL 320     // colsum partial blocks
#define FPAD 17        // f64 LDS row pad: bank=(34*lx+..)%32=2lx.. -> conflict-free

typedef short bf16x8 __attribute__((ext_vector_type(8)));   // 8 bf16 (4 VGPRs)
typedef float f32x4 __attribute__((ext_vector_type(4)));
typedef double f64x4 __attribute__((ext_vector_type(4)));

// ---- packed sort key: high 18 bits = monotone fp32, low 14 = 16383-idx ----
__device__ __forceinline__ unsigned pack_key(float v, int idx)
{
    unsigned b = __float_as_uint(v);
    unsigned m = b ^ ((unsigned)((int)b >> 31) | 0x80000000u);  // order-preserving
    return (m & 0xFFFFC000u) | (16383u - (unsigned)idx);
}

// sorted-descending insert on packed keys (v_min/v_max bubble)
template <int D>
__device__ __forceinline__ void insert_u(unsigned (&k)[D], unsigned nk)
{
    if (nk > k[D - 1]) {
        k[D - 1] = nk;
#pragma unroll
        for (int s = D - 1; s > 0; s--) {
            unsigned hi = max(k[s], k[s - 1]);
            unsigned lo = min(k[s], k[s - 1]);
            k[s - 1] = hi; k[s] = lo;
        }
    }
}

__device__ __forceinline__ void gload16(const void* g, void* l)
{
    __builtin_amdgcn_global_load_lds(
        (const __attribute__((address_space(1))) void*)g,
        (__attribute__((address_space(3))) void*)l, 16, 0, 0);
}

// --------------------------- column mean of h (f64) ------------------------
__global__ __launch_bounds__(256) void colsum_part64(
    const double* __restrict__ h, double* __restrict__ part, int n, int nb)
{
    int b = blockIdx.x;
    int rows_per = (n + nb - 1) / nb;
    int r0 = b * rows_per, r1 = min(n, r0 + rows_per);
    int t = threadIdx.x;
    double s0 = 0.0, s1 = 0.0;
    for (int i = r0; i < r1; i++) {
        s0 += h[(size_t)i * DIM + t];
        s1 += h[(size_t)i * DIM + t + 256];
    }
    part[b * DIM + t] = s0;
    part[b * DIM + t + 256] = s1;
}

__global__ void colmean64(const double* __restrict__ part, double* __restrict__ mean,
                          int nb, int n)
{
    int j = blockIdx.x * blockDim.x + threadIdx.x;
    if (j < DIM) {
        double s = 0.0;
        for (int b = 0; b < nb; b++) s += part[b * DIM + j];
        mean[j] = s / (double)n;
    }
}

// kv_w and lin_w f32 -> bf16, 4 elems/thread
__global__ void cast_wb(const float* __restrict__ in1, short* __restrict__ o1, int n1,
                        const float* __restrict__ in2, short* __restrict__ o2)
{
    int i = (blockIdx.x * blockDim.x + threadIdx.x) * 4;
    const float* in = (i < n1) ? in1 + i : in2 + (i - n1);
    short* o = (i < n1) ? o1 + i : o2 + (i - n1);
    float4 f = *(const float4*)in;
    __hip_bfloat16 b0 = __float2bfloat16(f.x), b1 = __float2bfloat16(f.y);
    __hip_bfloat16 b2 = __float2bfloat16(f.z), b3 = __float2bfloat16(f.w);
    *(short4*)o = make_short4(*(short*)&b0, *(short*)&b1, *(short*)&b2, *(short*)&b3);
}

// -------------- f64 MFMA GEMM for fc1:  h = leaky(x @ fc1^T + b) ------------
// BM=64, BN=128, BK=16; XCD-grouped 1D grid: c=id&7, y=(id>>3)&3,
// bx=c+8*(id>>5) -> all 4 j-panels of an A-panel on one XCD (L2 reuse).
__global__ __launch_bounds__(256, 4) void gemm_fc1(
    const float* __restrict__ X, const float* __restrict__ W,
    const float* __restrict__ bias, double* __restrict__ C, int n)
{
    const int K = DIM, M = DIM;
    const int id = blockIdx.x;
    const int c = id & 7, kk2 = id >> 3;
    const int y = kk2 & 3, mm = kk2 >> 2;
    const int bx = c + 8 * mm;
    if (bx >= (n + 63) / 64) return;

    __shared__ double As[64][FPAD];
    __shared__ double Bs[128][FPAD];
    const int t = threadIdx.x, lane = t & 63, wid = t >> 6;
    const int lx = lane & 15, q = lane >> 4;
    const int wr = (wid >> 1) * 32, wc = (wid & 1) * 64;
    const int i0 = bx * 64, j0 = y * 128;

    f64x4 acc[2][4];
#pragma unroll
    for (int a = 0; a < 2; a++)
#pragma unroll
        for (int b = 0; b < 4; b++) acc[a][b] = (f64x4)0.0;

    const int arow = t >> 2, askq = (t & 3) * 4;
    int gi = i0 + arow; if (gi >= n) gi = n - 1;
    const float* af32 = X + (size_t)gi * K + askq;
    const int brow = t >> 1, bskq = (t & 1) * 8;
    const float* wrow = W + (size_t)(j0 + brow) * K + bskq;

    float4 wv0 = *(const float4*)(wrow);
    float4 wv1 = *(const float4*)(wrow + 4);
    float4 av = *(const float4*)(af32);

    for (int k0 = 0; k0 < K; k0 += 16) {
        __syncthreads();
        As[arow][askq]     = (double)av.x; As[arow][askq + 1] = (double)av.y;
        As[arow][askq + 2] = (double)av.z; As[arow][askq + 3] = (double)av.w;
        Bs[brow][bskq]     = (double)wv0.x; Bs[brow][bskq + 1] = (double)wv0.y;
        Bs[brow][bskq + 2] = (double)wv0.z; Bs[brow][bskq + 3] = (double)wv0.w;
        Bs[brow][bskq + 4] = (double)wv1.x; Bs[brow][bskq + 5] = (double)wv1.y;
        Bs[brow][bskq + 6] = (double)wv1.z; Bs[brow][bskq + 7] = (double)wv1.w;
        if (k0 + 16 < K) {
            wv0 = *(const float4*)(wrow + k0 + 16);
            wv1 = *(const float4*)(wrow + k0 + 20);
            av  = *(const float4*)(af32 + k0 + 16);
        }
        __syncthreads();

#pragma unroll
        for (int ks = 0; ks < 4; ks++) {
            double a0 = As[wr + lx][ks * 4 + q];
            double a1 = As[wr + 16 + lx][ks * 4 + q];
#pragma unroll
            for (int cf = 0; cf < 4; cf++) {
                double b = Bs[wc + cf * 16 + lx][ks * 4 + q];
                acc[0][cf] = __builtin_amdgcn_mfma_f64_16x16x4f64(a0, b, acc[0][cf], 0, 0, 0);
                acc[1][cf] = __builtin_amdgcn_mfma_f64_16x16x4f64(a1, b, acc[1][cf], 0, 0, 0);
            }
        }
    }

#pragma unroll
    for (int rf = 0; rf < 2; rf++)
#pragma unroll
        for (int cf = 0; cf < 4; cf++)
#pragma unroll
            for (int reg = 0; reg < 4; reg++) {
                int gi2 = i0 + wr + rf * 16 + q * 4 + reg;
                int gj2 = j0 + wc + cf * 16 + lx;
                if (gi2 < n) {
                    double v = acc[rf][cf][reg] + (double)bias[gj2];
                    v = (v >= 0.0) ? v : v * SLOPE;
                    C[(size_t)gi2 * M + gj2] = v;
                }
            }
}

// ---- f64 MFMA dual GEMM: e_h AND e_t = ((h+mean)*0.5) @ w^T + b, fused -----
// XCD-grouped 1D grid (1280): c=id&7, y=(id>>3)&7, bx=c+8*(id>>6).
// (256,4): VGPR cap 128 >= ~130 live set is tight but verified non-spilling
// (R11: VGPR 64 arch + acc in AGPR half, WRITE_SIZE 127MB = pure output).
__global__ __launch_bounds__(256, 4) void gemm_ehet(
    const double* __restrict__ H, const float* __restrict__ whw,
    const float* __restrict__ whb, const float* __restrict__ wtw,
    const float* __restrict__ wtb, const double* __restrict__ mn,
    double* __restrict__ ehd, float* __restrict__ ehf, short* __restrict__ ehb2,
    double* __restrict__ etd, short* __restrict__ etb2, int n)
{
    const int K = DIM, M = DIM;
    const int id = blockIdx.x;
    const int c = id & 7, kk2 = id >> 3;
    const int y = kk2 & 7, mm = kk2 >> 3;
    const int bx = c + 8 * mm;
    if (bx >= (n + 63) / 64) return;
    const bool isH = (y < 4);
    const float* W    = isH ? whw : wtw;
    const float* bias = isH ? whb : wtb;
    double* C  = isH ? ehd : etd;
    short*  ob = isH ? ehb2 : etb2;

    __shared__ double As[64][FPAD];
    __shared__ double Bs[128][FPAD];
    const int t = threadIdx.x, lane = t & 63, wid = t >> 6;
    const int lx = lane & 15, q = lane >> 4;
    const int wr = (wid >> 1) * 32, wc = (wid & 1) * 64;
    const int i0 = bx * 64, j0 = (y & 3) * 128;

    f64x4 acc[2][4];
#pragma unroll
    for (int a = 0; a < 2; a++)
#pragma unroll
        for (int b = 0; b < 4; b++) acc[a][b] = (f64x4)0.0;

    const int arow = t >> 2, askq = (t & 3) * 4;
    int gi = i0 + arow; if (gi >= n) gi = n - 1;
    const double* af64 = H + (size_t)gi * K + askq;
    const int brow = t >> 1, bskq = (t & 1) * 8;
    const float* wrow = W + (size_t)(j0 + brow) * K + bskq;

    float4 wv0 = *(const float4*)(wrow);
    float4 wv1 = *(const float4*)(wrow + 4);
    double2 a0v = *(const double2*)(af64);
    double2 a1v = *(const double2*)(af64 + 2);

    for (int k0 = 0; k0 < K; k0 += 16) {
        __syncthreads();
        double2 mv0 = *(const double2*)(mn + k0 + askq);
        double2 mv1 = *(const double2*)(mn + k0 + askq + 2);
        As[arow][askq]     = (a0v.x + mv0.x) * 0.5; As[arow][askq + 1] = (a0v.y + mv0.y) * 0.5;
        As[arow][askq + 2] = (a1v.x + mv1.x) * 0.5; As[arow][askq + 3] = (a1v.y + mv1.y) * 0.5;
        Bs[brow][bskq]     = (double)wv0.x; Bs[brow][bskq + 1] = (double)wv0.y;
        Bs[brow][bskq + 2] = (double)wv0.z; Bs[brow][bskq + 3] = (double)wv0.w;
        Bs[brow][bskq + 4] = (double)wv1.x; Bs[brow][bskq + 5] = (double)wv1.y;
        Bs[brow][bskq + 6] = (double)wv1.z; Bs[brow][bskq + 7] = (double)wv1.w;
        if (k0 + 16 < K) {
            wv0 = *(const float4*)(wrow + k0 + 16);
            wv1 = *(const float4*)(wrow + k0 + 20);
            a0v = *(const double2*)(af64 + k0 + 16);
            a1v = *(const double2*)(af64 + k0 + 18);
        }
        __syncthreads();

#pragma unroll
        for (int ks = 0; ks < 4; ks++) {
            double a0 = As[wr + lx][ks * 4 + q];
            double a1 = As[wr + 16 + lx][ks * 4 + q];
#pragma unroll
            for (int cf = 0; cf < 4; cf++) {
                double b = Bs[wc + cf * 16 + lx][ks * 4 + q];
                acc[0][cf] = __builtin_amdgcn_mfma_f64_16x16x4f64(a0, b, acc[0][cf], 0, 0, 0);
                acc[1][cf] = __builtin_amdgcn_mfma_f64_16x16x4f64(a1, b, acc[1][cf], 0, 0, 0);
            }
        }
    }

#pragma unroll
    for (int rf = 0; rf < 2; rf++)
#pragma unroll
        for (int cf = 0; cf < 4; cf++)
#pragma unroll
            for (int reg = 0; reg < 4; reg++) {
                int gi2 = i0 + wr + rf * 16 + q * 4 + reg;
                int gj2 = j0 + wc + cf * 16 + lx;
                if (gi2 < n) {
                    double v = acc[rf][cf][reg] + (double)bias[gj2];
                    size_t idx = (size_t)gi2 * M + gj2;
                    C[idx] = v;
                    float f = (float)v;
                    if (isH) ehf[idx] = f;
                    __hip_bfloat16 bb = __float2bfloat16(f);
                    ob[idx] = *reinterpret_cast<short*>(&bb);
                }
            }
}

// ---------------- bf16 MFMA logits + fused per-chunk top-8 -----------------
// EXACT R6 structure (203 us): grid 790, XCD-affinity decode, CHUNK=1024,
// BK=32, 2 LDS buffers (32 KB), m97 2-barrier skeleton, packed-key top lists.
__global__ __launch_bounds__(256, 3) void logits_topk_mfma(
    const short* __restrict__ eh, const short* __restrict__ et,
    unsigned* __restrict__ pk, int n)
{
    __shared__ short As[2][4096];   // 128 rows x 32 shorts
    __shared__ short Bs[2][4096];
    const int t = threadIdx.x;
    const int lane = t & 63, wid = t >> 6;
    const int lx = lane & 15, q = lane >> 4;

    int id = blockIdx.x, bx, chunk;
    if (id < 632) { chunk = id & 7; bx = id >> 3; }
    else { int r = id - 632; chunk = 8 + (r & 1); bx = r >> 1; }
    const int i0 = bx * 128;
    const int wbase = wid * 32;

    const int jlo = chunk * CHUNK;
    const int jhi = min(n, jlo + CHUNK);
    const int nj = (jhi - jlo + 127) >> 7;
    const int np = nj * 16;

    const int sslot = (t & 3) ^ ((t >> 3) & 3);
    const short* aP[2];
    const short* bP[2];
#pragma unroll
    for (int is = 0; is < 2; is++) {
        int row = is * 64 + (t >> 2);
        int ra = i0 + row; if (ra >= n) ra = n - 1;
        aP[is] = eh + (size_t)ra * DIM + sslot * 8;
    }
    const int slotq = (q ^ ((lx >> 1) & 3)) * 8;
    const int aOff = (wbase + lx) * 32 + slotq;
    const int bOff = lx * 32 + slotq;

    unsigned keys[8][NL];
#pragma unroll
    for (int r = 0; r < 8; r++)
#pragma unroll
        for (int s = 0; s < NL; s++) keys[r][s] = 0u;

    f32x4 acc[2][8];
#pragma unroll
    for (int rf = 0; rf < 2; rf++)
#pragma unroll
        for (int cf = 0; cf < 8; cf++) acc[rf][cf] = (f32x4)0.f;

    auto STAGE = [&](int buf, int ph) {
        int kk = ph & 15;
        if (kk == 0) {  // new j-tile: refresh B row pointers (1/16 stages)
            int j0 = jlo + (ph >> 4) * 128;
#pragma unroll
            for (int is = 0; is < 2; is++) {
                int row = is * 64 + (t >> 2);
                int rb = j0 + row; if (rb >= n) rb = n - 1;
                bP[is] = et + (size_t)rb * DIM + sslot * 8;
            }
        }
        int ko = kk * 32;
#pragma unroll
        for (int is = 0; is < 2; is++) {
            gload16(aP[is] + ko, &As[buf][is * 2048 + wid * 512]);
            gload16(bP[is] + ko, &Bs[buf][is * 2048 + wid * 512]);
        }
    };

    STAGE(0, 0);
    for (int p = 0; p < np; ++p) {
        __builtin_amdgcn_sched_barrier(0);
        __builtin_amdgcn_s_barrier();
        __builtin_amdgcn_sched_barrier(0);
        if (p + 1 < np) {
            STAGE((p + 1) & 1, p + 1);
            asm volatile("s_waitcnt vmcnt(4)" ::: "memory");
        } else {
            asm volatile("s_waitcnt vmcnt(0)" ::: "memory");
        }
        __builtin_amdgcn_sched_barrier(0);
        __builtin_amdgcn_s_barrier();
        __builtin_amdgcn_sched_barrier(0);

        const short* Ab = As[p & 1];
        const short* Bb = Bs[p & 1];
        bf16x8 a0 = *(const bf16x8*)(Ab + aOff);
        bf16x8 a1 = *(const bf16x8*)(Ab + aOff + 512);
#pragma unroll
        for (int cf = 0; cf < 8; cf++) {
            bf16x8 bw = *(const bf16x8*)(Bb + bOff + cf * 512);
            acc[0][cf] = __builtin_amdgcn_mfma_f32_16x16x32_bf16(
                a0, bw, acc[0][cf], 0, 0, 0);
            acc[1][cf] = __builtin_amdgcn_mfma_f32_16x16x32_bf16(
                a1, bw, acc[1][cf], 0, 0, 0);
        }

        if ((p & 15) == 15) {   // end of a j-tile: pack+insert top-4, reset acc
            int j0 = jlo + (p >> 4) * 128;
#pragma unroll
            for (int rf = 0; rf < 2; rf++)
#pragma unroll
                for (int cf = 0; cf < 8; cf++) {
                    int gj = j0 + cf * 16 + lx;
                    if (gj < n) {
#pragma unroll
                        for (int reg = 0; reg < 4; reg++)
                            insert_u<NL>(keys[rf * 4 + reg],
                                         pack_key(acc[rf][cf][reg], gj));
                    }
                    acc[rf][cf] = (f32x4)0.f;
                }
        }
    }

    // butterfly merge across the 16-lane group -> per-(chunk,row) top-8
#pragma unroll
    for (int rr = 0; rr < 8; rr++) {
        unsigned mk[NCK];
#pragma unroll
        for (int s = 0; s < NL; s++) mk[s] = keys[rr][s];
#pragma unroll
        for (int s = NL; s < NCK; s++) mk[s] = 0u;
        for (int m = 1; m < 16; m <<= 1) {
            unsigned sv[NCK];
#pragma unroll
            for (int s = 0; s < NCK; s++) sv[s] = mk[s];
#pragma unroll
            for (int s = 0; s < NCK; s++) {
                unsigned ov = (unsigned)__shfl_xor((int)sv[s], m);
                insert_u<NCK>(mk, ov);
            }
        }
        if (lx == 0) {
            int rf = rr >> 2, reg = rr & 3;
            int grow = i0 + wbase + rf * 16 + q * 4 + reg;
            if (grow < n) {
#pragma unroll
                for (int s = 0; s < NCK; s++)
                    pk[((size_t)chunk * N_NODES + grow) * NCK + s] = mk[s];
            }
        }
    }
}

// ------------- bf16 MFMA GEMM:  C = post(A @ W^T + bias)  (K=512) ----------
// XCD-grouped 1D grid: c=id&7, y=(id>>3)&(NY-1), bx=c+8*(id>>(3+LY)).
template <int POST, int NY, int LY>
__global__ __launch_bounds__(256, 3) void mfma_gemm_bf16(
    const short* __restrict__ A, const short* __restrict__ W,
    const float* __restrict__ bias, const float* __restrict__ res,
    float* __restrict__ C, int n, int M)
{
    const int id = blockIdx.x;
    const int c = id & 7, kk2 = id >> 3;
    const int y = kk2 & (NY - 1), mm = kk2 >> LY;
    const int bxx = c + 8 * mm;
    if (bxx >= (n + 127) / 128) return;

    __shared__ short As[2][8192];
    __shared__ short Bs[2][8192];
    const int t = threadIdx.x;
    const int lane = t & 63, wid = t >> 6;
    const int lx = lane & 15, q = lane >> 4;
    const int lx7 = lane & 7;
    const int i0 = bxx * 128;
    const int j0 = y * 128;
    const int wbase = wid * 32;
    const int srl = lane >> 3;
    const int swz = (lane & 7) ^ srl;

    const short* aP[4];
    const short* bP[4];
#pragma unroll
    for (int is = 0; is < 4; is++) {
        int ra = i0 + is * 32 + wid * 8 + srl; if (ra >= n) ra = n - 1;
        aP[is] = A + (size_t)ra * DIM + swz * 8;
        int rb = j0 + is * 32 + wid * 8 + srl;   // M multiple of 128
        bP[is] = W + (size_t)rb * DIM + swz * 8;
    }
    int aIdx[2], bIdx[2];
#pragma unroll
    for (int ks = 0; ks < 2; ks++) {
        int kap = (ks * 4 + q) ^ lx7;
        aIdx[ks] = (wbase + lx) * 64 + kap * 8;
        bIdx[ks] = lx * 64 + kap * 8;
    }

    f32x4 acc[2][8];
#pragma unroll
    for (int rf = 0; rf < 2; rf++)
#pragma unroll
        for (int cf = 0; cf < 8; cf++) acc[rf][cf] = (f32x4)0.f;

    auto STAGE = [&](int buf, int kk) {
        int ko = kk * 64;
        short* ab = &As[buf][wid * 512];
        short* bb = &Bs[buf][wid * 512];
#pragma unroll
        for (int is = 0; is < 4; is++) {
            gload16(aP[is] + ko, ab + is * 2048);
            gload16(bP[is] + ko, bb + is * 2048);
        }
    };

    STAGE(0, 0);
    for (int p = 0; p < 8; ++p) {
        __builtin_amdgcn_sched_barrier(0);
        __builtin_amdgcn_s_barrier();
        __builtin_amdgcn_sched_barrier(0);
        if (p + 1 < 8) {
            STAGE((p + 1) & 1, p + 1);
            asm volatile("s_waitcnt vmcnt(8)" ::: "memory");
        } else {
            asm volatile("s_waitcnt vmcnt(0)" ::: "memory");
        }
        __builtin_amdgcn_sched_barrier(0);
        __builtin_amdgcn_s_barrier();
        __builtin_amdgcn_sched_barrier(0);

        const short* Ab = As[p & 1];
        const short* Bb = Bs[p & 1];
#pragma unroll
        for (int ks = 0; ks < 2; ks++) {
            bf16x8 a0 = *(const bf16x8*)(Ab + aIdx[ks]);
            bf16x8 a1 = *(const bf16x8*)(Ab + aIdx[ks] + 1024);
#pragma unroll
            for (int cf = 0; cf < 8; cf++) {
                bf16x8 bw = *(const bf16x8*)(Bb + bIdx[ks] + cf * 1024);
                acc[0][cf] = __builtin_amdgcn_mfma_f32_16x16x32_bf16(
                    a0, bw, acc[0][cf], 0, 0, 0);
                acc[1][cf] = __builtin_amdgcn_mfma_f32_16x16x32_bf16(
                    a1, bw, acc[1][cf], 0, 0, 0);
            }
        }
    }

#pragma unroll
    for (int rf = 0; rf < 2; rf++)
#pragma unroll
        for (int cf = 0; cf < 8; cf++)
#pragma unroll
            for (int reg = 0; reg < 4; reg++) {
                int gi = i0 + wbase + rf * 16 + q * 4 + reg;
                int gj = j0 + cf * 16 + lx;
                if (gi < n) {
                    float v = acc[rf][cf][reg] + bias[gj];
                    if (POST >= 1) v = (v >= 0.f) ? v : v * SLOPE;
                    if (POST == 2) v += res[(size_t)gi * M + gj];
                    C[(size_t)gi * M + gj] = v;
                }
            }
}

// merge 10 chunk-lists of 8 packed keys -> top-16 indices per row
__global__ void merge_chunks16(const unsigned* __restrict__ pk,
                               int* __restrict__ cand, int n)
{
    int row = blockIdx.x * blockDim.x + threadIdx.x;
    if (row >= n) return;
    unsigned bk[NC2];
#pragma unroll
    for (int s = 0; s < NC2; s++) bk[s] = 0u;
    for (int c = 0; c < NCHUNK; c++) {
#pragma unroll
        for (int s = 0; s < NCK; s++)
            insert_u<NC2>(bk, pk[((size_t)c * n + row) * NCK + s]);
    }
#pragma unroll
    for (int s = 0; s < NC2; s++)
        cand[row * NC2 + s] = 16383 - (int)(bk[s] & 16383u);
}

// ------- f64 re-rank of the 16 candidates + fused neighbor counting --------
__global__ __launch_bounds__(256) void refine16(
    const double* __restrict__ ehd, const double* __restrict__ etd,
    const int* __restrict__ cand, int* __restrict__ tki,
    int* __restrict__ counts, int n)
{
    int row = blockIdx.x * 4 + (threadIdx.x >> 6);
    if (row >= n) return;
    int lane = threadIdx.x & 63;
    int c = lane >> 2, sub = lane & 3;
    int j = cand[row * NC2 + c];
    const double* er = ehd + (size_t)row * DIM;
    const double* tr = etd + (size_t)j * DIM;
    double s = 0.0;
#pragma unroll 8
    for (int k = sub; k < DIM; k += 4) s += er[k] * tr[k];
    s += __shfl_down(s, 2);
    s += __shfl_down(s, 1);
    double mine = __shfl(s, lane & ~3);
    int rank = 0;
#pragma unroll
    for (int m = 0; m < NC2; m++) {
        double vm = __shfl(s, m * 4);
        int jm = __shfl(j, m * 4);
        bool better = (vm > mine) || (vm == mine && jm < j);
        rank += better ? 1 : 0;
    }
    if (sub == 0 && rank < TOPK) {
        tki[row * TOPK + rank] = j;
        atomicAdd(&counts[j], 1);
    }
}

// ----------------------------- argmax / ins_top ----------------------------
__global__ __launch_bounds__(1024) void argmax_kernel(
    const int* __restrict__ counts, int n, const float* __restrict__ x,
    int* __restrict__ topn, float* __restrict__ out_ins)
{
    __shared__ unsigned long long red[1024];
    int t = threadIdx.x;
    unsigned long long best = 0;
    for (int j = t; j < n; j += 1024) {
        unsigned long long key =
            ((unsigned long long)(unsigned)counts[j] << 32) | (unsigned)(n - 1 - j);
        if (key > best) best = key;
    }
    red[t] = best;
    __syncthreads();
    for (int s = 512; s > 0; s >>= 1) {
        if (t < s && red[t + s] > red[t]) red[t] = red[t + s];
        __syncthreads();
    }
    int tn = n - 1 - (int)(red[0] & 0xffffffffu);
    if (t == 0) *topn = tn;
    if (t < DIM) out_ins[t] = x[(size_t)tn * DIM + t];
}

// ------------------------------- q heads -----------------------------------
__global__ __launch_bounds__(512) void qheads_kernel(
    const double* __restrict__ h2d, const double* __restrict__ mn,
    const int* __restrict__ topn, const float* __restrict__ qw,
    const float* __restrict__ qb, float* __restrict__ qh)
{
    __shared__ float qf[DIM];
    int t = threadIdx.x;
    int tn = *topn;
    qf[t] = (float)((h2d[(size_t)tn * DIM + t] + mn[t]) * 0.5);
    __syncthreads();
    int w = t >> 6, lane = t & 63;
    int jrow = blockIdx.x * 8 + w;
    float s = 0.f;
    for (int k = lane; k < DIM; k += 64) s += qf[k] * qw[(size_t)jrow * DIM + k];
#pragma unroll
    for (int m = 32; m > 0; m >>= 1) s += __shfl_down(s, m);
    if (lane == 0) qh[jrow] = (s + qb[jrow]) * 0.125f;
}

__global__ __launch_bounds__(512) void scores_kernel(
    const float* __restrict__ E, const float* __restrict__ qh, float* __restrict__ sc)
{
    int i = blockIdx.x;
    int t = threadIdx.x, w = t >> 6, lane = t & 63;
    float v = qh[t] * E[(size_t)i * 1024 + t];
#pragma unroll
    for (int m = 32; m > 0; m >>= 1) v += __shfl_down(v, m);
    if (lane == 0) sc[i * 8 + w] = v;
}

// ---------------- attention + 2x layernorm (one block per node) ------------
__global__ __launch_bounds__(512) void attn_ln_kernel(
    const float* __restrict__ E, const float* __restrict__ sc,
    const int* __restrict__ tki, const float* __restrict__ eh,
    const float* __restrict__ nw, const float* __restrict__ nbias,
    short* __restrict__ sprb, int n)
{
    __shared__ int nb[TOPK];
    __shared__ float red[16];
    __shared__ float stats[2];
    const int i = blockIdx.x;
    const int t = threadIdx.x;
    const int h = t >> 6, lane = t & 63;
    if (t < TOPK) nb[t] = tki[i * TOPK + t];
    __syncthreads();

    float myse = 0.f;
    if (lane < TOPK) myse = sc[(size_t)nb[lane] * 8 + h];
    float se[TOPK];
#pragma unroll
    for (int e = 0; e < TOPK; e++) se[e] = __shfl(myse, e);
    float mx = se[0];
#pragma unroll
    for (int e = 1; e < TOPK; e++) mx = fmaxf(mx, se[e]);
    float wsum = 0.f, w[TOPK];
#pragma unroll
    for (int e = 0; e < TOPK; e++) { w[e] = expf(se[e] - mx); wsum += w[e]; }
    float inv = 1.f / wsum;

    float o = 0.f;
#pragma unroll
    for (int e = 0; e < TOPK; e++) o += w[e] * E[(size_t)nb[e] * 1024 + 512 + t];
    o *= inv;

    float s1 = o, s2 = o * o;
#pragma unroll
    for (int m = 32; m > 0; m >>= 1) { s1 += __shfl_down(s1, m); s2 += __shfl_down(s2, m); }
    if (lane == 0) { red[h] = s1; red[h + 8] = s2; }
    __syncthreads();
    if (t == 0) {
        float a = 0.f, b = 0.f;
#pragma unroll
        for (int k = 0; k < 8; k++) { a += red[k]; b += red[k + 8]; }
        float mu = a * (1.f / 512.f);
        float var = b * (1.f / 512.f) - mu * mu;
        stats[0] = mu; stats[1] = rsqrtf(var + LN_EPS);
    }
    __syncthreads();
    float enh = (o - stats[0]) * stats[1] * nw[t] + nbias[t];
    float t2 = eh[(size_t)i * DIM + t] + enh;
    __syncthreads();

    s1 = t2; s2 = t2 * t2;
#pragma unroll
    for (int m = 32; m > 0; m >>= 1) { s1 += __shfl_down(s1, m); s2 += __shfl_down(s2, m); }
    if (lane == 0) { red[h] = s1; red[h + 8] = s2; }
    __syncthreads();
    if (t == 0) {
        float a = 0.f, b = 0.f;
#pragma unroll
        for (int k = 0; k < 8; k++) { a += red[k]; b += red[k + 8]; }
        float mu = a * (1.f / 512.f);
        float var = b * (1.f / 512.f) - mu * mu;
        stats[0] = mu; stats[1] = rsqrtf(var + LN_EPS);
    }
    __syncthreads();
    float sv = (t2 - stats[0]) * stats[1] * nw[t] + nbias[t];
    __hip_bfloat16 bb = __float2bfloat16(sv);
    sprb[(size_t)i * DIM + t] = *reinterpret_cast<short*>(&bb);
}

// ===========================================================================
extern "C" void kernel_launch(void* const* d_in, const int* in_sizes, int n_in,
                              void* d_out, int out_size, void* d_ws, size_t ws_size,
                              hipStream_t stream)
{
    const float* x     = (const float*)d_in[0];
    const float* fc1_w = (const float*)d_in[1];
    const float* fc1_b = (const float*)d_in[2];
    const float* wh_w  = (const float*)d_in[3];
    const float* wh_b  = (const float*)d_in[4];
    const float* wt_w  = (const float*)d_in[5];
    const float* wt_b  = (const float*)d_in[6];
    const float* q_w   = (const float*)d_in[7];
    const float* q_b   = (const float*)d_in[8];
    const float* kv_w  = (const float*)d_in[9];
    const float* kv_b  = (const float*)d_in[10];
    const float* lin_w = (const float*)d_in[11];
    const float* lin_b = (const float*)d_in[12];
    const float* nw    = (const float*)d_in[13];
    const float* nbias = (const float*)d_in[14];
    float* out = (float*)d_out;

    const int n = N_NODES;
    size_t off = 0;
    auto take = [&](size_t bytes) -> void* {
        void* p = (void*)((char*)d_ws + off);
        off += (bytes + 255) & ~(size_t)255;
        return p;
    };
    double* h2d  = (double*)take((size_t)n * DIM * 8);  // RAW h (mix fused later)
    double* ehd  = (double*)take((size_t)n * DIM * 8);
    double* etd  = (double*)take((size_t)n * DIM * 8);
    float*  ehf  = (float*)take((size_t)n * DIM * 4);
    short*  ehb  = (short*)take((size_t)n * DIM * 2);
    short*  etb  = (short*)take((size_t)n * DIM * 2);
    short*  sprb = (short*)take((size_t)n * DIM * 2);
    unsigned* pk = (unsigned*)take((size_t)NCHUNK * n * NCK * 4);
    int*    cand = (int*)take((size_t)n * NC2 * 4);
    int*    tki  = (int*)take((size_t)n * TOPK * 4);
    int*    counts = (int*)take((size_t)n * 4);
    int*    topn = (int*)take(256);
    float*  qh   = (float*)take(DIM * 4);
    float*  sc   = (float*)take((size_t)n * 8 * 4);
    double* part = (double*)take((size_t)NB_COL * DIM * 8);
    double* mean = (double*)take(DIM * 8);
    short*  kvwb = (short*)take((size_t)1024 * DIM * 2);
    short*  linwb = (short*)take((size_t)512 * DIM * 2);
    // alias (lifetimes disjoint, stream-ordered):
    float* E = (float*)h2d;   // n x 1024 f32: written after h2d's last read (qheads)

    hipMemsetAsync(counts, 0, n * sizeof(int), stream);

    dim3 b256(256);
    const int RB2 = (n + 127) / 128;  // 79

    // h_raw = leaky(x @ fc1^T + b)   [f64 MFMA, XCD-grouped grid 640]
    gemm_fc1<<<dim3(640), b256, 0, stream>>>(x, fc1_w, fc1_b, h2d, n);
    colsum_part64<<<dim3(NB_COL), b256, 0, stream>>>(h2d, part, n, NB_COL);
    colmean64<<<dim3(2), b256, 0, stream>>>(part, mean, NB_COL, n);
    // e_h AND e_t = ((h_raw+mean)*0.5) @ w^T + b  [dual f64 MFMA, casts fused]
    gemm_ehet<<<dim3(1280), b256, 0, stream>>>(
        h2d, wh_w, wh_b, wt_w, wt_b, mean, ehd, ehf, ehb, etd, etb, n);
    cast_wb<<<dim3((1536 * DIM) / 1024), b256, 0, stream>>>(
        kv_w, kvwb, 1024 * DIM, lin_w, linwb);

    // coarse bf16 MFMA logits -> per-chunk top-8 keys -> top-16 -> f64 re-rank
    logits_topk_mfma<<<dim3(632 + 2 * RB2), b256, 0, stream>>>(ehb, etb, pk, n);
    merge_chunks16<<<dim3((n + 255) / 256), b256, 0, stream>>>(pk, cand, n);
    refine16<<<dim3((n + 3) / 4), b256, 0, stream>>>(ehd, etd, cand, tki, counts, n);

    argmax_kernel<<<dim3(1), dim3(1024), 0, stream>>>(counts, n, x, topn,
                                                      out + (size_t)n * DIM);
    qheads_kernel<<<dim3(64), dim3(512), 0, stream>>>(h2d, mean, topn, q_w, q_b, qh);
    // E = e_t @ kv_w^T + kv_b   [bf16 MFMA, XCD-grouped grid 640]
    mfma_gemm_bf16<0, 8, 3><<<dim3(640), b256, 0, stream>>>(
        etb, kvwb, kv_b, nullptr, E, n, 1024);
    scores_kernel<<<dim3(n), dim3(512), 0, stream>>>(E, qh, sc);
    attn_ln_kernel<<<dim3(n), dim3(512), 0, stream>>>(E, sc, tki, ehf, nw, nbias, sprb, n);
    // embedding = leaky(s @ lin^T + b) + x   [bf16 MFMA, XCD-grouped grid 320]
    mfma_gemm_bf16<2, 4, 2><<<dim3(320), b256, 0, stream>>>(
        sprb, linwb, lin_b, x, out, n, 512);
}